// Round 1
// baseline (4427.516 us; speedup 1.0000x reference)
//
#include <hip/hip_runtime.h>

// DGCNN: B=8 graphs, P=4096 points, K=20 neighbors, H=128 hidden.
// Decomposition: edge MLP relu([xi, xj-xi]@W + b) == relu(c_i + u_j) with
//   c_i = xi@(Wtop - Wbot) + b,  u_j = xj@Wbot   (Wtop=W[0:D], Wbot=W[D:2D])
// so per layer: sqnorm -> feat GEMMs (c,u) -> fused kNN top-20 -> gather/max.

static constexpr int B_ = 8, P_ = 4096, K_ = 20, H_ = 128;
static constexpr float FINF = 3.0e38f;

// ---------------- squared norms ----------------
template <int D>
__global__ __launch_bounds__(256) void sq_kernel(const float* __restrict__ X,
                                                 float* __restrict__ sqn) {
  int p = blockIdx.x * 256 + threadIdx.x;  // over B*P
  const float* row = X + (size_t)p * D;
  float s = 0.f;
#pragma unroll
  for (int d = 0; d < D; ++d) s = fmaf(row[d], row[d], s);
  sqn[p] = s;
}

// ---------------- c_i / u_j GEMMs ----------------
template <int D>
__global__ __launch_bounds__(256) void feat_kernel(
    const float* __restrict__ X, const float* __restrict__ W,
    const float* __restrict__ bias, float* __restrict__ c_out,
    float* __restrict__ u_out) {
  const int h = threadIdx.x & (H_ - 1);
  const int pg = threadIdx.x >> 7;          // 0/1
  const int p0 = blockIdx.x * 8 + pg * 4;   // 4 points per thread
  float a0 = 0, a1 = 0, a2 = 0, a3 = 0, u0 = 0, u1 = 0, u2 = 0, u3 = 0;
  const float* xp = X + (size_t)p0 * D;
#pragma unroll 4
  for (int d = 0; d < D; ++d) {
    float wt = W[d * H_ + h];
    float wb = W[(D + d) * H_ + h];
    float x0 = xp[d], x1 = xp[D + d], x2 = xp[2 * D + d], x3 = xp[3 * D + d];
    a0 = fmaf(x0, wt, a0); u0 = fmaf(x0, wb, u0);
    a1 = fmaf(x1, wt, a1); u1 = fmaf(x1, wb, u1);
    a2 = fmaf(x2, wt, a2); u2 = fmaf(x2, wb, u2);
    a3 = fmaf(x3, wt, a3); u3 = fmaf(x3, wb, u3);
  }
  float bv = bias[h];
  c_out[(size_t)(p0 + 0) * H_ + h] = a0 - u0 + bv;
  c_out[(size_t)(p0 + 1) * H_ + h] = a1 - u1 + bv;
  c_out[(size_t)(p0 + 2) * H_ + h] = a2 - u2 + bv;
  c_out[(size_t)(p0 + 3) * H_ + h] = a3 - u3 + bv;
  u_out[(size_t)(p0 + 0) * H_ + h] = u0;
  u_out[(size_t)(p0 + 1) * H_ + h] = u1;
  u_out[(size_t)(p0 + 2) * H_ + h] = u2;
  u_out[(size_t)(p0 + 3) * H_ + h] = u3;
}

// ---------------- fused kNN (top-20 smallest of sq_j - 2*dot) ----------------
// Block: 256 threads = 64 rows x 4 j-splits. j tiles of 64 staged in LDS.
template <int D>
__global__ __launch_bounds__(256) void knn_kernel(const float* __restrict__ X,
                                                  const float* __restrict__ sqn,
                                                  int* __restrict__ idx_out) {
  constexpr int ROWS = 64, SPLIT = 4, TJ = 64;
  constexpr int LSTRIDE = (D == 3) ? 4 : (D + 4);  // pad to dodge bank conflicts
  __shared__ float smem[ROWS * SPLIT * K_ * 2];    // 40 KB (tile & merge overlay)

  const int tid = threadIdx.x;
  const int row_local = tid >> 2;
  const int r = tid & 3;
  const int bpg = P_ / ROWS;
  const int b = blockIdx.x / bpg;
  const int i = (blockIdx.x % bpg) * ROWS + row_local;
  const int gi = b * P_ + i;

  float xi[D];
  {
    const float* xrow = X + (size_t)gi * D;
#pragma unroll
    for (int d = 0; d < D; ++d) xi[d] = xrow[d];
  }

  float bd[K_];
  int bj[K_];
#pragma unroll
  for (int k = 0; k < K_; ++k) { bd[k] = FINF; bj[k] = 0; }
  float worst = FINF;

  float* xjt = smem;
  float* sqs = smem + TJ * LSTRIDE;

  for (int tb = 0; tb < P_; tb += TJ) {
    __syncthreads();
    if (D == 3) {
      for (int t = tid; t < TJ; t += 256) {
        const float* p = X + (size_t)(b * P_ + tb + t) * 3;
        float4 v;
        v.x = p[0]; v.y = p[1]; v.z = p[2];
        v.w = sqn[b * P_ + tb + t];
        *(float4*)&xjt[t * 4] = v;
      }
    } else {
      const float4* src = (const float4*)(X + (size_t)(b * P_ + tb) * D);
      constexpr int NV = TJ * D / 4;
      for (int f = tid; f < NV; f += 256) {
        int jl = f / (D / 4), q = f % (D / 4);
        *(float4*)&xjt[jl * LSTRIDE + q * 4] = src[f];
      }
      if (tid < TJ) sqs[tid] = sqn[b * P_ + tb + tid];
    }
    __syncthreads();

#pragma unroll 2
    for (int jj = 0; jj < TJ / SPLIT; ++jj) {
      const int jl = r + SPLIT * jj;
      const int jg = tb + jl;
      float s;
      if (D == 3) {
        float4 v = *(const float4*)&xjt[jl * 4];
        s = v.w - 2.f * (xi[0] * v.x + xi[1] * v.y + xi[2] * v.z);
      } else {
        const float4* bv = (const float4*)&xjt[jl * LSTRIDE];
        float d0 = 0.f, d1 = 0.f;
#pragma unroll
        for (int q = 0; q < D / 4; q += 2) {
          float4 v0 = bv[q], v1 = bv[q + 1];
          d0 = fmaf(xi[4 * q + 0], v0.x, d0);
          d0 = fmaf(xi[4 * q + 1], v0.y, d0);
          d0 = fmaf(xi[4 * q + 2], v0.z, d0);
          d0 = fmaf(xi[4 * q + 3], v0.w, d0);
          d1 = fmaf(xi[4 * q + 4], v1.x, d1);
          d1 = fmaf(xi[4 * q + 5], v1.y, d1);
          d1 = fmaf(xi[4 * q + 6], v1.z, d1);
          d1 = fmaf(xi[4 * q + 7], v1.w, d1);
        }
        s = sqs[jl] - 2.f * (d0 + d1);
      }
      if (jg != i && s < worst) {
        bool done = false;
#pragma unroll
        for (int k = 0; k < K_; ++k) {
          if (!done && bd[k] == worst) { bd[k] = s; bj[k] = jg; done = true; }
        }
        worst = bd[0];
#pragma unroll
        for (int k = 1; k < K_; ++k) worst = fmaxf(worst, bd[k]);
      }
    }
  }

  // merge the 4 partial top-20s per row
  __syncthreads();
  float* md = smem;
  int* mj = (int*)(smem + ROWS * SPLIT * K_);
#pragma unroll
  for (int k = 0; k < K_; ++k) {
    md[(row_local * SPLIT + r) * K_ + k] = bd[k];
    mj[(row_local * SPLIT + r) * K_ + k] = bj[k];
  }
  __syncthreads();
  if (r == 0) {
    float* rowd = md + row_local * SPLIT * K_;
    int* rowj = mj + row_local * SPLIT * K_;
    int* outp = idx_out + (size_t)gi * K_;
    for (int sel = 0; sel < K_; ++sel) {
      float m = rowd[0];
      int arg = 0;
#pragma unroll 4
      for (int t = 1; t < SPLIT * K_; ++t) {
        if (rowd[t] < m) { m = rowd[t]; arg = t; }
      }
      outp[sel] = rowj[arg];
      rowd[arg] = FINF;
    }
  }
}

// ---------------- gather + max aggregation (in-place into c) ----------------
__global__ __launch_bounds__(256) void aggr_kernel(const float* __restrict__ c,
                                                   const float* __restrict__ u,
                                                   const int* __restrict__ nbr,
                                                   float* __restrict__ out) {
  int g = blockIdx.x * 256 + threadIdx.x;  // over B*P*H
  int h = g & (H_ - 1);
  int i = g >> 7;       // global point
  int b = i >> 12;      // P=4096
  const int* nb = nbr + (size_t)i * K_;
  float ci = c[g];
  float m = 0.f;  // relu floor
#pragma unroll
  for (int k = 0; k < K_; ++k) {
    int j = nb[k];
    float v = ci + u[(size_t)(b * P_ + j) * H_ + h];
    m = fmaxf(m, v);
  }
  out[g] = m;
}

// ---------------- head: mean pool + MLP ----------------
__global__ void zero_kernel(float* __restrict__ gsum) {
  gsum[threadIdx.x + blockIdx.x * 256] = 0.f;
}

__global__ __launch_bounds__(128) void pool_kernel(const float* __restrict__ hf,
                                                   float* __restrict__ gsum) {
  constexpr int CHUNK = 64;
  int blk = blockIdx.x;
  int b = blk / (P_ / CHUNK);
  int chunk = blk % (P_ / CHUNK);
  int h = threadIdx.x;
  int base = b * P_ + chunk * CHUNK;
  float acc = 0.f;
#pragma unroll 4
  for (int p = 0; p < CHUNK; ++p) acc += hf[(size_t)(base + p) * H_ + h];
  atomicAdd(&gsum[b * H_ + h], acc);
}

__global__ __launch_bounds__(128) void head_kernel(
    const float* __restrict__ gsum, const float* __restrict__ W4,
    const float* __restrict__ b4, const float* __restrict__ W5,
    const float* __restrict__ b5, float* __restrict__ out) {
  int b = blockIdx.x, h = threadIdx.x;
  __shared__ float g[H_];
  __shared__ float t[H_];
  g[h] = gsum[b * H_ + h] * (1.0f / P_);
  __syncthreads();
  float acc = b4[h];
#pragma unroll 4
  for (int d = 0; d < H_; ++d) acc = fmaf(g[d], W4[d * H_ + h], acc);
  t[h] = fmaxf(acc, 0.f);
  __syncthreads();
  if (h < 3) {
    float o = b5[h];
#pragma unroll 4
    for (int d = 0; d < H_; ++d) o = fmaf(t[d], W5[d * 3 + h], o);
    out[b * 3 + h] = o;
  }
}

extern "C" void kernel_launch(void* const* d_in, const int* in_sizes, int n_in,
                              void* d_out, int out_size, void* d_ws,
                              size_t ws_size, hipStream_t stream) {
  const float* x  = (const float*)d_in[0];
  const float* W1 = (const float*)d_in[1];
  const float* b1 = (const float*)d_in[2];
  const float* W2 = (const float*)d_in[3];
  const float* b2 = (const float*)d_in[4];
  const float* W3 = (const float*)d_in[5];
  const float* b3 = (const float*)d_in[6];
  const float* W4 = (const float*)d_in[7];
  const float* b4 = (const float*)d_in[8];
  const float* W5 = (const float*)d_in[9];
  const float* b5 = (const float*)d_in[10];
  float* out = (float*)d_out;

  char* ws = (char*)d_ws;
  const size_t NF = (size_t)B_ * P_ * H_;  // 4,194,304 floats
  float* bufA = (float*)ws;            ws += NF * 4;
  float* bufB = (float*)ws;            ws += NF * 4;
  float* bufU = (float*)ws;            ws += NF * 4;
  float* sqn  = (float*)ws;            ws += (size_t)B_ * P_ * 4;
  int*   nbr  = (int*)ws;              ws += (size_t)B_ * P_ * K_ * 4;
  float* gsum = (float*)ws;            ws += (size_t)B_ * H_ * 4;

  const int NP = B_ * P_;
  dim3 blk256(256), blk128(128);

  // ---- layer 1 (D=3), X = input, c->bufA, u->bufU, out(in-place)->bufA
  sq_kernel<3><<<NP / 256, blk256, 0, stream>>>(x, sqn);
  feat_kernel<3><<<NP / 8, blk256, 0, stream>>>(x, W1, b1, bufA, bufU);
  knn_kernel<3><<<B_ * (P_ / 64), blk256, 0, stream>>>(x, sqn, nbr);
  aggr_kernel<<<(NP * H_) / 256, blk256, 0, stream>>>(bufA, bufU, nbr, bufA);

  // ---- layer 2 (D=128), X = bufA, c->bufB, out->bufB
  sq_kernel<128><<<NP / 256, blk256, 0, stream>>>(bufA, sqn);
  feat_kernel<128><<<NP / 8, blk256, 0, stream>>>(bufA, W2, b2, bufB, bufU);
  knn_kernel<128><<<B_ * (P_ / 64), blk256, 0, stream>>>(bufA, sqn, nbr);
  aggr_kernel<<<(NP * H_) / 256, blk256, 0, stream>>>(bufB, bufU, nbr, bufB);

  // ---- layer 3 (D=128), X = bufB, c->bufA, out->bufA
  sq_kernel<128><<<NP / 256, blk256, 0, stream>>>(bufB, sqn);
  feat_kernel<128><<<NP / 8, blk256, 0, stream>>>(bufB, W3, b3, bufA, bufU);
  knn_kernel<128><<<B_ * (P_ / 64), blk256, 0, stream>>>(bufB, sqn, nbr);
  aggr_kernel<<<(NP * H_) / 256, blk256, 0, stream>>>(bufA, bufU, nbr, bufA);

  // ---- head
  zero_kernel<<<(B_ * H_) / 256, blk256, 0, stream>>>(gsum);
  pool_kernel<<<B_ * (P_ / 64), blk128, 0, stream>>>(bufA, gsum);
  head_kernel<<<B_, blk128, 0, stream>>>(gsum, W4, b4, W5, b5, out);
}

// Round 2
// 3147.920 us; speedup vs baseline: 1.4065x; 1.4065x over previous
//
#include <hip/hip_runtime.h>
#include <hip/hip_bf16.h>

// DGCNN: B=8, P=4096, K=20, H=128.
// EdgeConv decomposition: relu([xi, xj-xi]@W + b) == relu(c_i + u_j).
// kNN gram via MFMA with split-bf16 (x=hi+lo; dot = hh + hl + lh, ~2^-17 rel err).

static constexpr int B_ = 8, P_ = 4096, K_ = 20, H_ = 128;
static constexpr float FINF = 3.0e38f;

typedef __attribute__((ext_vector_type(8))) short short8;
typedef __attribute__((ext_vector_type(4))) float floatx4;

// ---------------- squared norms ----------------
template <int D>
__global__ __launch_bounds__(256) void sq_kernel(const float* __restrict__ X,
                                                 float* __restrict__ sqn) {
  int p = blockIdx.x * 256 + threadIdx.x;  // over B*P
  const float* row = X + (size_t)p * D;
  float s = 0.f;
#pragma unroll
  for (int d = 0; d < D; ++d) s = fmaf(row[d], row[d], s);
  sqn[p] = s;
}

// ---------------- f32 -> bf16 hi/lo split ----------------
__global__ __launch_bounds__(256) void split_kernel(const float* __restrict__ X,
                                                    ushort* __restrict__ hi,
                                                    ushort* __restrict__ lo) {
  int g = (blockIdx.x * 256 + threadIdx.x) * 4;
  float4 v = *(const float4*)(X + g);
  ushort4 h, l;
#define CVT(c)                                        \
  {                                                   \
    __hip_bfloat16 hb = __float2bfloat16(v.c);        \
    float hf = __bfloat162float(hb);                  \
    __hip_bfloat16 lb = __float2bfloat16(v.c - hf);   \
    h.c = *(ushort*)&hb;                              \
    l.c = *(ushort*)&lb;                              \
  }
  CVT(x) CVT(y) CVT(z) CVT(w)
#undef CVT
  *(ushort4*)(hi + g) = h;
  *(ushort4*)(lo + g) = l;
}

// ---------------- c_i / u_j GEMMs ----------------
template <int D>
__global__ __launch_bounds__(256) void feat_kernel(
    const float* __restrict__ X, const float* __restrict__ W,
    const float* __restrict__ bias, float* __restrict__ c_out,
    float* __restrict__ u_out) {
  const int h = threadIdx.x & (H_ - 1);
  const int pg = threadIdx.x >> 7;          // 0/1
  const int p0 = blockIdx.x * 8 + pg * 4;   // 4 points per thread
  float a0 = 0, a1 = 0, a2 = 0, a3 = 0, u0 = 0, u1 = 0, u2 = 0, u3 = 0;
  const float* xp = X + (size_t)p0 * D;
#pragma unroll 4
  for (int d = 0; d < D; ++d) {
    float wt = W[d * H_ + h];
    float wb = W[(D + d) * H_ + h];
    float x0 = xp[d], x1 = xp[D + d], x2 = xp[2 * D + d], x3 = xp[3 * D + d];
    a0 = fmaf(x0, wt, a0); u0 = fmaf(x0, wb, u0);
    a1 = fmaf(x1, wt, a1); u1 = fmaf(x1, wb, u1);
    a2 = fmaf(x2, wt, a2); u2 = fmaf(x2, wb, u2);
    a3 = fmaf(x3, wt, a3); u3 = fmaf(x3, wb, u3);
  }
  float bv = bias[h];
  c_out[(size_t)(p0 + 0) * H_ + h] = a0 - u0 + bv;
  c_out[(size_t)(p0 + 1) * H_ + h] = a1 - u1 + bv;
  c_out[(size_t)(p0 + 2) * H_ + h] = a2 - u2 + bv;
  c_out[(size_t)(p0 + 3) * H_ + h] = a3 - u3 + bv;
  u_out[(size_t)(p0 + 0) * H_ + h] = u0;
  u_out[(size_t)(p0 + 1) * H_ + h] = u1;
  u_out[(size_t)(p0 + 2) * H_ + h] = u2;
  u_out[(size_t)(p0 + 3) * H_ + h] = u3;
}

// ---------------- D=3 kNN (f32, cheap) ----------------
__global__ __launch_bounds__(256) void knn3_kernel(const float* __restrict__ X,
                                                   const float* __restrict__ sqn,
                                                   int* __restrict__ idx_out) {
  constexpr int ROWS = 64, SPLIT = 4, TJ = 64;
  __shared__ float smem[ROWS * SPLIT * K_ * 2];  // 40 KB

  const int tid = threadIdx.x;
  const int row_local = tid >> 2;
  const int r = tid & 3;
  const int bpg = P_ / ROWS;
  const int b = blockIdx.x / bpg;
  const int i = (blockIdx.x % bpg) * ROWS + row_local;
  const int gi = b * P_ + i;

  float xi0, xi1, xi2;
  {
    const float* xrow = X + (size_t)gi * 3;
    xi0 = xrow[0]; xi1 = xrow[1]; xi2 = xrow[2];
  }

  float bd[K_];
  int bj[K_];
#pragma unroll
  for (int k = 0; k < K_; ++k) { bd[k] = FINF; bj[k] = 0; }
  float worst = FINF;

  float* xjt = smem;

  for (int tb = 0; tb < P_; tb += TJ) {
    __syncthreads();
    for (int t = tid; t < TJ; t += 256) {
      const float* p = X + (size_t)(b * P_ + tb + t) * 3;
      float4 v;
      v.x = p[0]; v.y = p[1]; v.z = p[2];
      v.w = sqn[b * P_ + tb + t];
      *(float4*)&xjt[t * 4] = v;
    }
    __syncthreads();

#pragma unroll 4
    for (int jj = 0; jj < TJ / SPLIT; ++jj) {
      const int jl = r + SPLIT * jj;
      const int jg = tb + jl;
      float4 v = *(const float4*)&xjt[jl * 4];
      float s = v.w - 2.f * (xi0 * v.x + xi1 * v.y + xi2 * v.z);
      if (s < worst && jg != i) {
        bool done = false;
#pragma unroll
        for (int k = 0; k < K_; ++k) {
          if (!done && bd[k] == worst) { bd[k] = s; bj[k] = jg; done = true; }
        }
        worst = bd[0];
#pragma unroll
        for (int k = 1; k < K_; ++k) worst = fmaxf(worst, bd[k]);
      }
    }
  }

  __syncthreads();
  float* md = smem;
  int* mj = (int*)(smem + ROWS * SPLIT * K_);
#pragma unroll
  for (int k = 0; k < K_; ++k) {
    md[(row_local * SPLIT + r) * K_ + k] = bd[k];
    mj[(row_local * SPLIT + r) * K_ + k] = bj[k];
  }
  __syncthreads();
  if (r == 0) {
    float* rowd = md + row_local * SPLIT * K_;
    int* rowj = mj + row_local * SPLIT * K_;
    int* outp = idx_out + (size_t)gi * K_;
    for (int sel = 0; sel < K_; ++sel) {
      float m = rowd[0];
      int arg = 0;
#pragma unroll 4
      for (int t = 1; t < SPLIT * K_; ++t) {
        if (rowd[t] < m) { m = rowd[t]; arg = t; }
      }
      outp[sel] = rowj[arg];
      rowd[arg] = FINF;
    }
  }
}

// ---------------- D=128 kNN via MFMA split-bf16 ----------------
// Block: 256 thr = 4 waves; 64 i-rows (16/wave), j chunks of 64.
__global__ __launch_bounds__(256) void knn_mfma_kernel(
    const ushort* __restrict__ Xhi, const ushort* __restrict__ Xlo,
    const float* __restrict__ sqn, int* __restrict__ idx_out) {
  constexpr int ROWS = 64, TJ = 64, SPLIT = 4;
  constexpr int PSTR = 136;  // staged ushorts per point (128 + 8 pad)
  constexpr int DSTR = 65;   // dist-tile floats per row
  __shared__ int4 smem_raw[3232];  // 51712 B
  ushort* ljhi = (ushort*)smem_raw;                   // 17408 B
  ushort* ljlo = ljhi + TJ * PSTR;                    // 17408 B
  float* lsq = (float*)(ljlo + TJ * PSTR);            // 256 B
  float* ldist = lsq + TJ;                            // 64*65*4 = 16640 B

  const int tid = threadIdx.x;
  const int lane = tid & 63;
  const int w = tid >> 6;
  const int quad = lane >> 4;
  const int col = lane & 15;
  const int bpg = P_ / ROWS;  // 64
  const int b = blockIdx.x / bpg;
  const int i0 = (blockIdx.x % bpg) * ROWS;
  const size_t gb = (size_t)b * P_;

  // A fragments (rows i0 + w*16 + col), 4 k-steps of 32 dims, hi & lo
  short8 ahi[4], alo[4];
  {
    const size_t arow = (gb + i0 + w * 16 + col) * (size_t)H_;
#pragma unroll
    for (int s = 0; s < 4; ++s) {
      ahi[s] = *(const short8*)(Xhi + arow + s * 32 + quad * 8);
      alo[s] = *(const short8*)(Xlo + arow + s * 32 + quad * 8);
    }
  }

  // top-k state (scan identity)
  const int srow = tid >> 2;  // 0..63
  const int sr = tid & 3;     // 0..3, scans j = sr*16..+15 of each chunk
  const int gi = i0 + srow;   // within-graph row
  float bd[K_];
  int bj[K_];
#pragma unroll
  for (int k = 0; k < K_; ++k) { bd[k] = FINF; bj[k] = 0; }
  float worst = FINF;

  int prev_tb = -1;
  for (int tb = 0; tb < P_; tb += TJ) {
    __syncthreads();  // prev compute done reading ljhi/ljlo; ldist ready
    // ---- stage chunk tb (global -> LDS, 16B vectors)
#pragma unroll
    for (int it = 0; it < 4; ++it) {
      int f = tid + it * 256;  // 0..1023
      int p = f >> 4, q = f & 15;
      const size_t src = (gb + tb + p) * (size_t)H_ + q * 8;
      *(int4*)(ljhi + p * PSTR + q * 8) = *(const int4*)(Xhi + src);
      *(int4*)(ljlo + p * PSTR + q * 8) = *(const int4*)(Xlo + src);
    }
    if (tid < TJ) lsq[tid] = sqn[gb + tb + tid];
    // ---- scan previous chunk's dist tile (overlaps staging)
    if (prev_tb >= 0) {
      const float* drow = ldist + srow * DSTR + sr * 16;
#pragma unroll 4
      for (int jj = 0; jj < 16; ++jj) {
        float s = drow[jj];
        int jg = prev_tb + sr * 16 + jj;
        if (s < worst && jg != gi) {
          bool done = false;
#pragma unroll
          for (int k = 0; k < K_; ++k) {
            if (!done && bd[k] == worst) { bd[k] = s; bj[k] = jg; done = true; }
          }
          worst = bd[0];
#pragma unroll
          for (int k = 1; k < K_; ++k) worst = fmaxf(worst, bd[k]);
        }
      }
    }
    __syncthreads();
    // ---- MFMA: dists for chunk tb
    floatx4 acc[4];
#pragma unroll
    for (int t = 0; t < 4; ++t) acc[t] = (floatx4){0.f, 0.f, 0.f, 0.f};
#pragma unroll
    for (int s = 0; s < 4; ++s) {
      short8 bh[4], bl[4];
#pragma unroll
      for (int t = 0; t < 4; ++t) {
        const ushort* bp = ljhi + (t * 16 + col) * PSTR + s * 32 + quad * 8;
        bh[t] = *(const short8*)bp;
        bl[t] = *(const short8*)(bp + TJ * PSTR);
      }
#pragma unroll
      for (int t = 0; t < 4; ++t) {
        acc[t] = __builtin_amdgcn_mfma_f32_16x16x32_bf16(ahi[s], bh[t], acc[t], 0, 0, 0);
        acc[t] = __builtin_amdgcn_mfma_f32_16x16x32_bf16(ahi[s], bl[t], acc[t], 0, 0, 0);
        acc[t] = __builtin_amdgcn_mfma_f32_16x16x32_bf16(alo[s], bh[t], acc[t], 0, 0, 0);
      }
    }
    // ---- store d2 = sq_j - 2*dot into dist tile
#pragma unroll
    for (int t = 0; t < 4; ++t) {
      float sqv = lsq[t * 16 + col];
#pragma unroll
      for (int reg = 0; reg < 4; ++reg) {
        int rl = w * 16 + quad * 4 + reg;
        ldist[rl * DSTR + t * 16 + col] = fmaf(-2.f, acc[t][reg], sqv);
      }
    }
    prev_tb = tb;
  }
  // ---- epilogue: scan last chunk
  __syncthreads();
  {
    const float* drow = ldist + srow * DSTR + sr * 16;
#pragma unroll 4
    for (int jj = 0; jj < 16; ++jj) {
      float s = drow[jj];
      int jg = prev_tb + sr * 16 + jj;
      if (s < worst && jg != gi) {
        bool done = false;
#pragma unroll
        for (int k = 0; k < K_; ++k) {
          if (!done && bd[k] == worst) { bd[k] = s; bj[k] = jg; done = true; }
        }
        worst = bd[0];
#pragma unroll
        for (int k = 1; k < K_; ++k) worst = fmaxf(worst, bd[k]);
      }
    }
  }
  // ---- merge 4 partial top-20s per row (overlay on smem)
  __syncthreads();
  float* md = (float*)smem_raw;
  int* mj = (int*)(md + ROWS * SPLIT * K_);
#pragma unroll
  for (int k = 0; k < K_; ++k) {
    md[(srow * SPLIT + sr) * K_ + k] = bd[k];
    mj[(srow * SPLIT + sr) * K_ + k] = bj[k];
  }
  __syncthreads();
  if (sr == 0) {
    float* rowd = md + srow * SPLIT * K_;
    int* rowj = mj + srow * SPLIT * K_;
    int* outp = idx_out + (gb + gi) * K_;
    for (int sel = 0; sel < K_; ++sel) {
      float m = rowd[0];
      int arg = 0;
#pragma unroll 4
      for (int t = 1; t < SPLIT * K_; ++t) {
        if (rowd[t] < m) { m = rowd[t]; arg = t; }
      }
      outp[sel] = rowj[arg];
      rowd[arg] = FINF;
    }
  }
}

// ---------------- gather + max aggregation ----------------
__global__ __launch_bounds__(256) void aggr_kernel(const float* __restrict__ c,
                                                   const float* __restrict__ u,
                                                   const int* __restrict__ nbr,
                                                   float* __restrict__ out) {
  int g = blockIdx.x * 256 + threadIdx.x;  // over B*P*H
  int h = g & (H_ - 1);
  int i = g >> 7;       // global point
  int b = i >> 12;      // P=4096
  const int* nb = nbr + (size_t)i * K_;
  float ci = c[g];
  float m = 0.f;  // relu floor
#pragma unroll
  for (int k = 0; k < K_; ++k) {
    int j = nb[k];
    float v = ci + u[(size_t)(b * P_ + j) * H_ + h];
    m = fmaxf(m, v);
  }
  out[g] = m;
}

// ---------------- head: mean pool + MLP ----------------
__global__ void zero_kernel(float* __restrict__ gsum) {
  gsum[threadIdx.x + blockIdx.x * 256] = 0.f;
}

__global__ __launch_bounds__(128) void pool_kernel(const float* __restrict__ hf,
                                                   float* __restrict__ gsum) {
  constexpr int CHUNK = 64;
  int blk = blockIdx.x;
  int b = blk / (P_ / CHUNK);
  int chunk = blk % (P_ / CHUNK);
  int h = threadIdx.x;
  int base = b * P_ + chunk * CHUNK;
  float acc = 0.f;
#pragma unroll 4
  for (int p = 0; p < CHUNK; ++p) acc += hf[(size_t)(base + p) * H_ + h];
  atomicAdd(&gsum[b * H_ + h], acc);
}

__global__ __launch_bounds__(128) void head_kernel(
    const float* __restrict__ gsum, const float* __restrict__ W4,
    const float* __restrict__ b4, const float* __restrict__ W5,
    const float* __restrict__ b5, float* __restrict__ out) {
  int b = blockIdx.x, h = threadIdx.x;
  __shared__ float g[H_];
  __shared__ float t[H_];
  g[h] = gsum[b * H_ + h] * (1.0f / P_);
  __syncthreads();
  float acc = b4[h];
#pragma unroll 4
  for (int d = 0; d < H_; ++d) acc = fmaf(g[d], W4[d * H_ + h], acc);
  t[h] = fmaxf(acc, 0.f);
  __syncthreads();
  if (h < 3) {
    float o = b5[h];
#pragma unroll 4
    for (int d = 0; d < H_; ++d) o = fmaf(t[d], W5[d * 3 + h], o);
    out[b * 3 + h] = o;
  }
}

extern "C" void kernel_launch(void* const* d_in, const int* in_sizes, int n_in,
                              void* d_out, int out_size, void* d_ws,
                              size_t ws_size, hipStream_t stream) {
  const float* x  = (const float*)d_in[0];
  const float* W1 = (const float*)d_in[1];
  const float* b1 = (const float*)d_in[2];
  const float* W2 = (const float*)d_in[3];
  const float* b2 = (const float*)d_in[4];
  const float* W3 = (const float*)d_in[5];
  const float* b3 = (const float*)d_in[6];
  const float* W4 = (const float*)d_in[7];
  const float* b4 = (const float*)d_in[8];
  const float* W5 = (const float*)d_in[9];
  const float* b5 = (const float*)d_in[10];
  float* out = (float*)d_out;

  char* ws = (char*)d_ws;
  const size_t NF = (size_t)B_ * P_ * H_;  // 4,194,304
  float* bufA = (float*)ws;            ws += NF * 4;
  float* bufB = (float*)ws;            ws += NF * 4;
  float* bufU = (float*)ws;            ws += NF * 4;
  ushort* xhi = (ushort*)ws;           ws += NF * 2;
  ushort* xlo = (ushort*)ws;           ws += NF * 2;
  float* sqn  = (float*)ws;            ws += (size_t)B_ * P_ * 4;
  int*   nbr  = (int*)ws;              ws += (size_t)B_ * P_ * K_ * 4;
  float* gsum = (float*)ws;            ws += (size_t)B_ * H_ * 4;

  const int NP = B_ * P_;
  dim3 blk256(256), blk128(128);

  // ---- layer 1 (D=3)
  sq_kernel<3><<<NP / 256, blk256, 0, stream>>>(x, sqn);
  feat_kernel<3><<<NP / 8, blk256, 0, stream>>>(x, W1, b1, bufA, bufU);
  knn3_kernel<<<B_ * (P_ / 64), blk256, 0, stream>>>(x, sqn, nbr);
  aggr_kernel<<<(NP * H_) / 256, blk256, 0, stream>>>(bufA, bufU, nbr, bufA);

  // ---- layer 2 (D=128), X = bufA
  split_kernel<<<(int)(NF / 4 / 256), blk256, 0, stream>>>(bufA, xhi, xlo);
  sq_kernel<128><<<NP / 256, blk256, 0, stream>>>(bufA, sqn);
  feat_kernel<128><<<NP / 8, blk256, 0, stream>>>(bufA, W2, b2, bufB, bufU);
  knn_mfma_kernel<<<B_ * (P_ / 64), blk256, 0, stream>>>(xhi, xlo, sqn, nbr);
  aggr_kernel<<<(NP * H_) / 256, blk256, 0, stream>>>(bufB, bufU, nbr, bufB);

  // ---- layer 3 (D=128), X = bufB
  split_kernel<<<(int)(NF / 4 / 256), blk256, 0, stream>>>(bufB, xhi, xlo);
  sq_kernel<128><<<NP / 256, blk256, 0, stream>>>(bufB, sqn);
  feat_kernel<128><<<NP / 8, blk256, 0, stream>>>(bufB, W3, b3, bufA, bufU);
  knn_mfma_kernel<<<B_ * (P_ / 64), blk256, 0, stream>>>(xhi, xlo, sqn, nbr);
  aggr_kernel<<<(NP * H_) / 256, blk256, 0, stream>>>(bufA, bufU, nbr, bufA);

  // ---- head
  zero_kernel<<<(B_ * H_) / 256, blk256, 0, stream>>>(gsum);
  pool_kernel<<<B_ * (P_ / 64), blk128, 0, stream>>>(bufA, gsum);
  head_kernel<<<B_, blk128, 0, stream>>>(gsum, W4, b4, W5, b5, out);
}

// Round 3
// 2410.048 us; speedup vs baseline: 1.8371x; 1.3062x over previous
//
#include <hip/hip_runtime.h>
#include <hip/hip_bf16.h>

// DGCNN: B=8, P=4096, K=20, H=128.
// EdgeConv: relu([xi, xj-xi]@W + b) == relu(c_i + u_j).
// kNN gram via MFMA split-bf16; selection via threshold compaction:
//   tau = exact 20th of a 512-j window (upper bound of global 20th)
//   -> ballot-compact survivors (d<=tau) -> exact top-20 of survivors.

static constexpr int B_ = 8, P_ = 4096, K_ = 20, H_ = 128;
static constexpr float FINF = 3.0e38f;
static constexpr int CAP = 192;  // survivor cap per row per j-half (E~80, ~6 sigma)

typedef __attribute__((ext_vector_type(8))) short short8;
typedef __attribute__((ext_vector_type(4))) float floatx4;

// ---------------- squared norms ----------------
template <int D>
__global__ __launch_bounds__(256) void sq_kernel(const float* __restrict__ X,
                                                 float* __restrict__ sqn) {
  int p = blockIdx.x * 256 + threadIdx.x;
  const float* row = X + (size_t)p * D;
  float s = 0.f;
#pragma unroll
  for (int d = 0; d < D; ++d) s = fmaf(row[d], row[d], s);
  sqn[p] = s;
}

// ---------------- f32 -> bf16 hi/lo split ----------------
__global__ __launch_bounds__(256) void split_kernel(const float* __restrict__ X,
                                                    ushort* __restrict__ hi,
                                                    ushort* __restrict__ lo) {
  int g = (blockIdx.x * 256 + threadIdx.x) * 4;
  float4 v = *(const float4*)(X + g);
  ushort4 h, l;
#define CVT(c)                                        \
  {                                                   \
    __hip_bfloat16 hb = __float2bfloat16(v.c);        \
    float hf = __bfloat162float(hb);                  \
    __hip_bfloat16 lb = __float2bfloat16(v.c - hf);   \
    h.c = *(ushort*)&hb;                              \
    l.c = *(ushort*)&lb;                              \
  }
  CVT(x) CVT(y) CVT(z) CVT(w)
#undef CVT
  *(ushort4*)(hi + g) = h;
  *(ushort4*)(lo + g) = l;
}

// ---------------- c_i / u_j GEMMs ----------------
template <int D>
__global__ __launch_bounds__(256) void feat_kernel(
    const float* __restrict__ X, const float* __restrict__ W,
    const float* __restrict__ bias, float* __restrict__ c_out,
    float* __restrict__ u_out) {
  const int h = threadIdx.x & (H_ - 1);
  const int pg = threadIdx.x >> 7;
  const int p0 = blockIdx.x * 8 + pg * 4;
  float a0 = 0, a1 = 0, a2 = 0, a3 = 0, u0 = 0, u1 = 0, u2 = 0, u3 = 0;
  const float* xp = X + (size_t)p0 * D;
#pragma unroll 4
  for (int d = 0; d < D; ++d) {
    float wt = W[d * H_ + h];
    float wb = W[(D + d) * H_ + h];
    float x0 = xp[d], x1 = xp[D + d], x2 = xp[2 * D + d], x3 = xp[3 * D + d];
    a0 = fmaf(x0, wt, a0); u0 = fmaf(x0, wb, u0);
    a1 = fmaf(x1, wt, a1); u1 = fmaf(x1, wb, u1);
    a2 = fmaf(x2, wt, a2); u2 = fmaf(x2, wb, u2);
    a3 = fmaf(x3, wt, a3); u3 = fmaf(x3, wb, u3);
  }
  float bv = bias[h];
  c_out[(size_t)(p0 + 0) * H_ + h] = a0 - u0 + bv;
  c_out[(size_t)(p0 + 1) * H_ + h] = a1 - u1 + bv;
  c_out[(size_t)(p0 + 2) * H_ + h] = a2 - u2 + bv;
  c_out[(size_t)(p0 + 3) * H_ + h] = a3 - u3 + bv;
  u_out[(size_t)(p0 + 0) * H_ + h] = u0;
  u_out[(size_t)(p0 + 1) * H_ + h] = u1;
  u_out[(size_t)(p0 + 2) * H_ + h] = u2;
  u_out[(size_t)(p0 + 3) * H_ + h] = u3;
}

// ---------------- D=3 kNN (f32, cheap) ----------------
__global__ __launch_bounds__(256) void knn3_kernel(const float* __restrict__ X,
                                                   const float* __restrict__ sqn,
                                                   int* __restrict__ idx_out) {
  constexpr int ROWS = 64, SPLIT = 4, TJ = 64;
  __shared__ float smem[ROWS * SPLIT * K_ * 2];

  const int tid = threadIdx.x;
  const int row_local = tid >> 2;
  const int r = tid & 3;
  const int bpg = P_ / ROWS;
  const int b = blockIdx.x / bpg;
  const int i = (blockIdx.x % bpg) * ROWS + row_local;
  const int gi = b * P_ + i;

  float xi0, xi1, xi2;
  {
    const float* xrow = X + (size_t)gi * 3;
    xi0 = xrow[0]; xi1 = xrow[1]; xi2 = xrow[2];
  }

  float bd[K_];
  int bj[K_];
#pragma unroll
  for (int k = 0; k < K_; ++k) { bd[k] = FINF; bj[k] = 0; }
  float worst = FINF;

  float* xjt = smem;

  for (int tb = 0; tb < P_; tb += TJ) {
    __syncthreads();
    for (int t = tid; t < TJ; t += 256) {
      const float* p = X + (size_t)(b * P_ + tb + t) * 3;
      float4 v;
      v.x = p[0]; v.y = p[1]; v.z = p[2];
      v.w = sqn[b * P_ + tb + t];
      *(float4*)&xjt[t * 4] = v;
    }
    __syncthreads();

#pragma unroll 4
    for (int jj = 0; jj < TJ / SPLIT; ++jj) {
      const int jl = r + SPLIT * jj;
      const int jg = tb + jl;
      float4 v = *(const float4*)&xjt[jl * 4];
      float s = v.w - 2.f * (xi0 * v.x + xi1 * v.y + xi2 * v.z);
      if (s < worst && jg != i) {
        bool done = false;
#pragma unroll
        for (int k = 0; k < K_; ++k) {
          if (!done && bd[k] == worst) { bd[k] = s; bj[k] = jg; done = true; }
        }
        worst = bd[0];
#pragma unroll
        for (int k = 1; k < K_; ++k) worst = fmaxf(worst, bd[k]);
      }
    }
  }

  __syncthreads();
  float* md = smem;
  int* mj = (int*)(smem + ROWS * SPLIT * K_);
#pragma unroll
  for (int k = 0; k < K_; ++k) {
    md[(row_local * SPLIT + r) * K_ + k] = bd[k];
    mj[(row_local * SPLIT + r) * K_ + k] = bj[k];
  }
  __syncthreads();
  if (r == 0) {
    float* rowd = md + row_local * SPLIT * K_;
    int* rowj = mj + row_local * SPLIT * K_;
    int* outp = idx_out + (size_t)gi * K_;
    for (int sel = 0; sel < K_; ++sel) {
      float m = rowd[0];
      int arg = 0;
#pragma unroll 4
      for (int t = 1; t < SPLIT * K_; ++t) {
        if (rowd[t] < m) { m = rowd[t]; arg = t; }
      }
      outp[sel] = rowj[arg];
      rowd[arg] = FINF;
    }
  }
}

// ---------------- A1: windowed partial top-20 distances (D=128, MFMA) ----
// grid = B * 64 rowgroups * 2 parts; each block: 64 rows x 256 js.
__global__ __launch_bounds__(256) void knn_part_kernel(
    const ushort* __restrict__ Xhi, const ushort* __restrict__ Xlo,
    const float* __restrict__ sqn, float* __restrict__ pd) {
  constexpr int ROWS = 64, TJ = 64, SPLIT = 4, NCH = 4;
  constexpr int PSTR = 136, DSTR = 65;
  __shared__ int4 smem_raw[3232];  // 51712 B
  ushort* ljhi = (ushort*)smem_raw;
  ushort* ljlo = ljhi + TJ * PSTR;
  float* lsq = (float*)(ljlo + TJ * PSTR);
  float* ldist = lsq + TJ;

  const int tid = threadIdx.x;
  const int lane = tid & 63;
  const int w = tid >> 6;
  const int quad = lane >> 4;
  const int col = lane & 15;
  const int part = blockIdx.x & 1;
  const int rgb = blockIdx.x >> 1;  // b*64 + rg
  const int b = rgb >> 6;
  const int i0 = (rgb & 63) * ROWS;
  const int jbase = part * (NCH * TJ);
  const size_t gb = (size_t)b * P_;

  short8 ahi[4], alo[4];
  {
    const size_t arow = (gb + i0 + w * 16 + col) * (size_t)H_;
#pragma unroll
    for (int s = 0; s < 4; ++s) {
      ahi[s] = *(const short8*)(Xhi + arow + s * 32 + quad * 8);
      alo[s] = *(const short8*)(Xlo + arow + s * 32 + quad * 8);
    }
  }

  const int srow = tid >> 2;
  const int sr = tid & 3;
  const int gi = i0 + srow;
  float bd[K_];
#pragma unroll
  for (int k = 0; k < K_; ++k) bd[k] = FINF;
  float worst = FINF;

  int prev_tb = -1;
  for (int c = 0; c < NCH; ++c) {
    const int tb = jbase + c * TJ;
    __syncthreads();
#pragma unroll
    for (int it = 0; it < 4; ++it) {
      int f = tid + it * 256;
      int p = f >> 4, q = f & 15;
      const size_t src = (gb + tb + p) * (size_t)H_ + q * 8;
      *(int4*)(ljhi + p * PSTR + q * 8) = *(const int4*)(Xhi + src);
      *(int4*)(ljlo + p * PSTR + q * 8) = *(const int4*)(Xlo + src);
    }
    if (tid < TJ) lsq[tid] = sqn[gb + tb + tid];
    if (prev_tb >= 0) {
      const float* drow = ldist + srow * DSTR + sr * 16;
#pragma unroll 4
      for (int jj = 0; jj < 16; ++jj) {
        float s = drow[jj];
        int jg = prev_tb + sr * 16 + jj;
        if (s < worst && jg != gi) {
          bool done = false;
#pragma unroll
          for (int k = 0; k < K_; ++k) {
            if (!done && bd[k] == worst) { bd[k] = s; done = true; }
          }
          worst = bd[0];
#pragma unroll
          for (int k = 1; k < K_; ++k) worst = fmaxf(worst, bd[k]);
        }
      }
    }
    __syncthreads();
    floatx4 acc[4];
#pragma unroll
    for (int t = 0; t < 4; ++t) acc[t] = (floatx4){0.f, 0.f, 0.f, 0.f};
#pragma unroll
    for (int s = 0; s < 4; ++s) {
      short8 bh[4], bl[4];
#pragma unroll
      for (int t = 0; t < 4; ++t) {
        const ushort* bp = ljhi + (t * 16 + col) * PSTR + s * 32 + quad * 8;
        bh[t] = *(const short8*)bp;
        bl[t] = *(const short8*)(bp + TJ * PSTR);
      }
#pragma unroll
      for (int t = 0; t < 4; ++t) {
        acc[t] = __builtin_amdgcn_mfma_f32_16x16x32_bf16(ahi[s], bh[t], acc[t], 0, 0, 0);
        acc[t] = __builtin_amdgcn_mfma_f32_16x16x32_bf16(ahi[s], bl[t], acc[t], 0, 0, 0);
        acc[t] = __builtin_amdgcn_mfma_f32_16x16x32_bf16(alo[s], bh[t], acc[t], 0, 0, 0);
      }
    }
#pragma unroll
    for (int t = 0; t < 4; ++t) {
      float sqv = lsq[t * 16 + col];
#pragma unroll
      for (int reg = 0; reg < 4; ++reg) {
        int rl = w * 16 + quad * 4 + reg;
        ldist[rl * DSTR + t * 16 + col] = fmaf(-2.f, acc[t][reg], sqv);
      }
    }
    prev_tb = tb;
  }
  __syncthreads();
  {
    const float* drow = ldist + srow * DSTR + sr * 16;
#pragma unroll 4
    for (int jj = 0; jj < 16; ++jj) {
      float s = drow[jj];
      int jg = prev_tb + sr * 16 + jj;
      if (s < worst && jg != gi) {
        bool done = false;
#pragma unroll
        for (int k = 0; k < K_; ++k) {
          if (!done && bd[k] == worst) { bd[k] = s; done = true; }
        }
        worst = bd[0];
#pragma unroll
        for (int k = 1; k < K_; ++k) worst = fmaxf(worst, bd[k]);
      }
    }
  }
  // merge 4 partials -> row top-20 distances of this 256-window part
  __syncthreads();
  float* md = (float*)smem_raw;
#pragma unroll
  for (int k = 0; k < K_; ++k) md[(srow * SPLIT + sr) * K_ + k] = bd[k];
  __syncthreads();
  if (sr == 0) {
    float* rowd = md + srow * SPLIT * K_;
    float* outp = pd + (gb + gi) * (2 * K_) + part * K_;
    for (int sel = 0; sel < K_; ++sel) {
      float m = rowd[0];
      int arg = 0;
#pragma unroll 4
      for (int t = 1; t < SPLIT * K_; ++t) {
        if (rowd[t] < m) { m = rowd[t]; arg = t; }
      }
      outp[sel] = m;
      rowd[arg] = FINF;
    }
  }
}

// ---------------- A2: tau = 20th smallest of the 40 window values ----------
__global__ __launch_bounds__(256) void tau_kernel(const float* __restrict__ pd,
                                                  float* __restrict__ tau) {
  int row = blockIdx.x * 256 + threadIdx.x;  // over B*P
  float v[40];
#pragma unroll
  for (int k = 0; k < 40; ++k) v[k] = pd[(size_t)row * 40 + k];
  float m = 0.f;
  for (int sel = 0; sel < K_; ++sel) {
    m = v[0];
#pragma unroll
    for (int t = 1; t < 40; ++t) m = fminf(m, v[t]);
    bool done = false;
#pragma unroll
    for (int t = 0; t < 40; ++t) {
      if (!done && v[t] == m) { v[t] = FINF; done = true; }
    }
  }
  tau[row] = m;
}

// ---------------- B: full scan + ballot compaction ----------------
// grid = B * 64 rowgroups * 2 j-halves; block: 64 rows x 2048 js.
__global__ __launch_bounds__(256) void knn_compact_kernel(
    const ushort* __restrict__ Xhi, const ushort* __restrict__ Xlo,
    const float* __restrict__ sqn, const float* __restrict__ tau,
    float2* __restrict__ cand, int* __restrict__ cnt) {
  constexpr int ROWS = 64, TJ = 64, NCH = 32;
  constexpr int PSTR = 136, DSTR = 65;
  __shared__ int4 smem_raw[3232];  // 51712 B
  ushort* ljhi = (ushort*)smem_raw;
  ushort* ljlo = ljhi + TJ * PSTR;
  float* lsq = (float*)(ljlo + TJ * PSTR);
  float* ldist = lsq + TJ;

  const int tid = threadIdx.x;
  const int lane = tid & 63;
  const int w = tid >> 6;
  const int quad = lane >> 4;
  const int col = lane & 15;
  const int half = blockIdx.x & 1;
  const int rgb = blockIdx.x >> 1;
  const int b = rgb >> 6;
  const int i0 = (rgb & 63) * ROWS;
  const int jbase = half * (NCH * TJ);
  const size_t gb = (size_t)b * P_;

  short8 ahi[4], alo[4];
  {
    const size_t arow = (gb + i0 + w * 16 + col) * (size_t)H_;
#pragma unroll
    for (int s = 0; s < 4; ++s) {
      ahi[s] = *(const short8*)(Xhi + arow + s * 32 + quad * 8);
      alo[s] = *(const short8*)(Xlo + arow + s * 32 + quad * 8);
    }
  }

  // per-wave rows w*16 + r : thresholds + cursors (wave-uniform)
  float taur[16];
  int cur[16];
#pragma unroll
  for (int r = 0; r < 16; ++r) {
    taur[r] = tau[gb + i0 + w * 16 + r];
    cur[r] = 0;
  }

  int prev_tb = -1;
  for (int c = 0; c < NCH; ++c) {
    const int tb = jbase + c * TJ;
    __syncthreads();
#pragma unroll
    for (int it = 0; it < 4; ++it) {
      int f = tid + it * 256;
      int p = f >> 4, q = f & 15;
      const size_t src = (gb + tb + p) * (size_t)H_ + q * 8;
      *(int4*)(ljhi + p * PSTR + q * 8) = *(const int4*)(Xhi + src);
      *(int4*)(ljlo + p * PSTR + q * 8) = *(const int4*)(Xlo + src);
    }
    if (tid < TJ) lsq[tid] = sqn[gb + tb + tid];
    // ---- compact previous chunk (wave-local ldist rows; overlaps staging)
    if (prev_tb >= 0) {
#pragma unroll
      for (int r = 0; r < 16; ++r) {
        float d = ldist[(w * 16 + r) * DSTR + lane];
        int jg = prev_tb + lane;
        bool pred = (d <= taur[r]) && (jg != i0 + w * 16 + r);
        unsigned long long mk = __ballot(pred);
        if (mk) {
          int n = __popcll(mk);
          int pre = __popcll(mk & ((1ull << lane) - 1ull));
          int idx = cur[r] + pre;
          if (pred && idx < CAP) {
            float2 e;
            e.x = d;
            e.y = __int_as_float(jg);
            cand[(gb + i0 + w * 16 + r) * (size_t)(2 * CAP) + half * CAP + idx] = e;
          }
          cur[r] += n;
        }
      }
    }
    __syncthreads();
    floatx4 acc[4];
#pragma unroll
    for (int t = 0; t < 4; ++t) acc[t] = (floatx4){0.f, 0.f, 0.f, 0.f};
#pragma unroll
    for (int s = 0; s < 4; ++s) {
      short8 bh[4], bl[4];
#pragma unroll
      for (int t = 0; t < 4; ++t) {
        const ushort* bp = ljhi + (t * 16 + col) * PSTR + s * 32 + quad * 8;
        bh[t] = *(const short8*)bp;
        bl[t] = *(const short8*)(bp + TJ * PSTR);
      }
#pragma unroll
      for (int t = 0; t < 4; ++t) {
        acc[t] = __builtin_amdgcn_mfma_f32_16x16x32_bf16(ahi[s], bh[t], acc[t], 0, 0, 0);
        acc[t] = __builtin_amdgcn_mfma_f32_16x16x32_bf16(ahi[s], bl[t], acc[t], 0, 0, 0);
        acc[t] = __builtin_amdgcn_mfma_f32_16x16x32_bf16(alo[s], bh[t], acc[t], 0, 0, 0);
      }
    }
#pragma unroll
    for (int t = 0; t < 4; ++t) {
      float sqv = lsq[t * 16 + col];
#pragma unroll
      for (int reg = 0; reg < 4; ++reg) {
        int rl = w * 16 + quad * 4 + reg;
        ldist[rl * DSTR + t * 16 + col] = fmaf(-2.f, acc[t][reg], sqv);
      }
    }
    prev_tb = tb;
  }
  // epilogue compact of the last chunk
  __syncthreads();
#pragma unroll
  for (int r = 0; r < 16; ++r) {
    float d = ldist[(w * 16 + r) * DSTR + lane];
    int jg = prev_tb + lane;
    bool pred = (d <= taur[r]) && (jg != i0 + w * 16 + r);
    unsigned long long mk = __ballot(pred);
    if (mk) {
      int n = __popcll(mk);
      int pre = __popcll(mk & ((1ull << lane) - 1ull));
      int idx = cur[r] + pre;
      if (pred && idx < CAP) {
        float2 e;
        e.x = d;
        e.y = __int_as_float(jg);
        cand[(gb + i0 + w * 16 + r) * (size_t)(2 * CAP) + half * CAP + idx] = e;
      }
      cur[r] += n;
    }
  }
  if (lane == 0) {
#pragma unroll
    for (int r = 0; r < 16; ++r) {
      cnt[(gb + i0 + w * 16 + r) * 2 + half] = cur[r] < CAP ? cur[r] : CAP;
    }
  }
}

// ---------------- C: exact top-20 of survivors (one wave per row) ---------
__global__ __launch_bounds__(256) void knn_select_kernel(
    const float2* __restrict__ cand, const int* __restrict__ cnt,
    int* __restrict__ nbr) {
  const int w = threadIdx.x >> 6;
  const int lane = threadIdx.x & 63;
  const int row = blockIdx.x * 4 + w;  // over B*P
  const int c0 = cnt[row * 2], c1 = cnt[row * 2 + 1];
  const int ctot = c0 + c1;
  float d[6];
  int j[6];
#pragma unroll
  for (int s = 0; s < 6; ++s) {
    int m = s * 64 + lane;
    bool valid = m < ctot;
    int addr = (m < c0) ? m : (CAP + m - c0);
    if (!valid) addr = 0;
    float2 e = cand[(size_t)row * (2 * CAP) + addr];
    d[s] = valid ? e.x : FINF;
    j[s] = __float_as_int(e.y);
  }
  int* outp = nbr + (size_t)row * K_;
  for (int round = 0; round < K_; ++round) {
    float bm = d[0];
    int bs = 0;
#pragma unroll
    for (int s = 1; s < 6; ++s) {
      if (d[s] < bm) { bm = d[s]; bs = s; }
    }
    int id = (lane << 3) | bs;
#pragma unroll
    for (int off = 1; off < 64; off <<= 1) {
      float od = __shfl_xor(bm, off);
      int oid = __shfl_xor(id, off);
      if (od < bm || (od == bm && oid < id)) { bm = od; id = oid; }
    }
    int owner = id >> 3, os = id & 7;
    if (lane == owner) {
      int jv = 0;
#pragma unroll
      for (int s = 0; s < 6; ++s) {
        if (s == os) { jv = j[s]; d[s] = FINF; }
      }
      outp[round] = jv;
    }
  }
}

// ---------------- gather + max aggregation ----------------
__global__ __launch_bounds__(256) void aggr_kernel(const float* __restrict__ c,
                                                   const float* __restrict__ u,
                                                   const int* __restrict__ nbr,
                                                   float* __restrict__ out) {
  int g = blockIdx.x * 256 + threadIdx.x;
  int h = g & (H_ - 1);
  int i = g >> 7;
  int b = i >> 12;
  const int* nb = nbr + (size_t)i * K_;
  float ci = c[g];
  float m = 0.f;
#pragma unroll
  for (int k = 0; k < K_; ++k) {
    int j = nb[k];
    float v = ci + u[(size_t)(b * P_ + j) * H_ + h];
    m = fmaxf(m, v);
  }
  out[g] = m;
}

// ---------------- head: mean pool + MLP ----------------
__global__ void zero_kernel(float* __restrict__ gsum) {
  gsum[threadIdx.x + blockIdx.x * 256] = 0.f;
}

__global__ __launch_bounds__(128) void pool_kernel(const float* __restrict__ hf,
                                                   float* __restrict__ gsum) {
  constexpr int CHUNK = 64;
  int blk = blockIdx.x;
  int b = blk / (P_ / CHUNK);
  int chunk = blk % (P_ / CHUNK);
  int h = threadIdx.x;
  int base = b * P_ + chunk * CHUNK;
  float acc = 0.f;
#pragma unroll 4
  for (int p = 0; p < CHUNK; ++p) acc += hf[(size_t)(base + p) * H_ + h];
  atomicAdd(&gsum[b * H_ + h], acc);
}

__global__ __launch_bounds__(128) void head_kernel(
    const float* __restrict__ gsum, const float* __restrict__ W4,
    const float* __restrict__ b4, const float* __restrict__ W5,
    const float* __restrict__ b5, float* __restrict__ out) {
  int b = blockIdx.x, h = threadIdx.x;
  __shared__ float g[H_];
  __shared__ float t[H_];
  g[h] = gsum[b * H_ + h] * (1.0f / P_);
  __syncthreads();
  float acc = b4[h];
#pragma unroll 4
  for (int d = 0; d < H_; ++d) acc = fmaf(g[d], W4[d * H_ + h], acc);
  t[h] = fmaxf(acc, 0.f);
  __syncthreads();
  if (h < 3) {
    float o = b5[h];
#pragma unroll 4
    for (int d = 0; d < H_; ++d) o = fmaf(t[d], W5[d * 3 + h], o);
    out[b * 3 + h] = o;
  }
}

extern "C" void kernel_launch(void* const* d_in, const int* in_sizes, int n_in,
                              void* d_out, int out_size, void* d_ws,
                              size_t ws_size, hipStream_t stream) {
  const float* x  = (const float*)d_in[0];
  const float* W1 = (const float*)d_in[1];
  const float* b1 = (const float*)d_in[2];
  const float* W2 = (const float*)d_in[3];
  const float* b2 = (const float*)d_in[4];
  const float* W3 = (const float*)d_in[5];
  const float* b3 = (const float*)d_in[6];
  const float* W4 = (const float*)d_in[7];
  const float* b4 = (const float*)d_in[8];
  const float* W5 = (const float*)d_in[9];
  const float* b5 = (const float*)d_in[10];
  float* out = (float*)d_out;

  char* ws = (char*)d_ws;
  const size_t NF = (size_t)B_ * P_ * H_;   // 4,194,304
  const size_t NP_ = (size_t)B_ * P_;       // 32768
  float*  bufA = (float*)ws;  ws += NF * 4;
  float*  bufB = (float*)ws;  ws += NF * 4;
  float*  bufU = (float*)ws;  ws += NF * 4;
  ushort* xhi  = (ushort*)ws; ws += NF * 2;
  ushort* xlo  = (ushort*)ws; ws += NF * 2;
  float*  sqn  = (float*)ws;  ws += NP_ * 4;
  int*    nbr  = (int*)ws;    ws += NP_ * K_ * 4;
  float*  gsum = (float*)ws;  ws += (size_t)B_ * H_ * 4;
  float*  pd   = (float*)ws;  ws += NP_ * 40 * 4;
  float*  tau  = (float*)ws;  ws += NP_ * 4;
  int*    cnt  = (int*)ws;    ws += NP_ * 2 * 4;
  float2* cand = (float2*)ws; ws += NP_ * (size_t)(2 * CAP) * 8;

  const int NP = B_ * P_;
  dim3 blk256(256), blk128(128);

  // ---- layer 1 (D=3)
  sq_kernel<3><<<NP / 256, blk256, 0, stream>>>(x, sqn);
  feat_kernel<3><<<NP / 8, blk256, 0, stream>>>(x, W1, b1, bufA, bufU);
  knn3_kernel<<<B_ * (P_ / 64), blk256, 0, stream>>>(x, sqn, nbr);
  aggr_kernel<<<(NP * H_) / 256, blk256, 0, stream>>>(bufA, bufU, nbr, bufA);

  // ---- layer 2 (D=128), X = bufA
  split_kernel<<<(int)(NF / 4 / 256), blk256, 0, stream>>>(bufA, xhi, xlo);
  sq_kernel<128><<<NP / 256, blk256, 0, stream>>>(bufA, sqn);
  feat_kernel<128><<<NP / 8, blk256, 0, stream>>>(bufA, W2, b2, bufB, bufU);
  knn_part_kernel<<<B_ * 64 * 2, blk256, 0, stream>>>(xhi, xlo, sqn, pd);
  tau_kernel<<<NP / 256, blk256, 0, stream>>>(pd, tau);
  knn_compact_kernel<<<B_ * 64 * 2, blk256, 0, stream>>>(xhi, xlo, sqn, tau, cand, cnt);
  knn_select_kernel<<<NP / 4, blk256, 0, stream>>>(cand, cnt, nbr);
  aggr_kernel<<<(NP * H_) / 256, blk256, 0, stream>>>(bufB, bufU, nbr, bufB);

  // ---- layer 3 (D=128), X = bufB
  split_kernel<<<(int)(NF / 4 / 256), blk256, 0, stream>>>(bufB, xhi, xlo);
  sq_kernel<128><<<NP / 256, blk256, 0, stream>>>(bufB, sqn);
  feat_kernel<128><<<NP / 8, blk256, 0, stream>>>(bufB, W3, b3, bufA, bufU);
  knn_part_kernel<<<B_ * 64 * 2, blk256, 0, stream>>>(xhi, xlo, sqn, pd);
  tau_kernel<<<NP / 256, blk256, 0, stream>>>(pd, tau);
  knn_compact_kernel<<<B_ * 64 * 2, blk256, 0, stream>>>(xhi, xlo, sqn, tau, cand, cnt);
  knn_select_kernel<<<NP / 4, blk256, 0, stream>>>(cand, cnt, nbr);
  aggr_kernel<<<(NP * H_) / 256, blk256, 0, stream>>>(bufA, bufU, nbr, bufA);

  // ---- head
  zero_kernel<<<(B_ * H_) / 256, blk256, 0, stream>>>(gsum);
  pool_kernel<<<B_ * (P_ / 64), blk128, 0, stream>>>(bufA, gsum);
  head_kernel<<<B_, blk128, 0, stream>>>(gsum, W4, b4, W5, b5, out);
}

// Round 4
// 1432.935 us; speedup vs baseline: 3.0898x; 1.6819x over previous
//
#include <hip/hip_runtime.h>
#include <hip/hip_bf16.h>

// DGCNN: B=8, P=4096, K=20, H=128.
// EdgeConv: relu([xi, xj-xi]@W + b) == relu(c_i + u_j).
// kNN: gram (MFMA split-bf16 for D=128, f32 for D=3); selection via
// threshold compaction: tau = exact 20th of >=20 distinct window values
// (upper bound of true 20th) -> ballot-compact d<=tau -> exact top-20.

static constexpr int B_ = 8, P_ = 4096, K_ = 20, H_ = 128;
static constexpr float FINF = 3.0e38f;
static constexpr int CAP = 192;  // survivors per row per j-half (E~80)
static constexpr int K8 = 8;     // per-split kept values for tau bound

typedef __attribute__((ext_vector_type(8))) short short8;
typedef __attribute__((ext_vector_type(4))) float floatx4;

__device__ __forceinline__ float dist3(float x0, float x1, float x2,
                                       const float4& v) {
  // MUST be bit-identical between part and compact kernels.
  return fmaf(-2.f, fmaf(x0, v.x, fmaf(x1, v.y, x2 * v.z)), v.w);
}

// ---------------- squared norms (D=128 layers) ----------------
template <int D>
__global__ __launch_bounds__(256) void sq_kernel(const float* __restrict__ X,
                                                 float* __restrict__ sqn) {
  int p = blockIdx.x * 256 + threadIdx.x;
  const float* row = X + (size_t)p * D;
  float s = 0.f;
#pragma unroll
  for (int d = 0; d < D; ++d) s = fmaf(row[d], row[d], s);
  sqn[p] = s;
}

// ---------------- pack (x,y,z,|x|^2) for layer-1 ----------------
__global__ __launch_bounds__(256) void pack4_kernel(const float* __restrict__ X,
                                                    float4* __restrict__ pt4) {
  int p = blockIdx.x * 256 + threadIdx.x;
  const float* row = X + (size_t)p * 3;
  float4 v;
  v.x = row[0]; v.y = row[1]; v.z = row[2];
  v.w = fmaf(v.x, v.x, fmaf(v.y, v.y, v.z * v.z));
  pt4[p] = v;
}

// ---------------- f32 -> bf16 hi/lo split ----------------
__global__ __launch_bounds__(256) void split_kernel(const float* __restrict__ X,
                                                    ushort* __restrict__ hi,
                                                    ushort* __restrict__ lo) {
  int g = (blockIdx.x * 256 + threadIdx.x) * 4;
  float4 v = *(const float4*)(X + g);
  ushort4 h, l;
#define CVT(c)                                        \
  {                                                   \
    __hip_bfloat16 hb = __float2bfloat16(v.c);        \
    float hf = __bfloat162float(hb);                  \
    __hip_bfloat16 lb = __float2bfloat16(v.c - hf);   \
    h.c = *(ushort*)&hb;                              \
    l.c = *(ushort*)&lb;                              \
  }
  CVT(x) CVT(y) CVT(z) CVT(w)
#undef CVT
  *(ushort4*)(hi + g) = h;
  *(ushort4*)(lo + g) = l;
}

// ---------------- c_i / u_j GEMMs ----------------
template <int D>
__global__ __launch_bounds__(256) void feat_kernel(
    const float* __restrict__ X, const float* __restrict__ W,
    const float* __restrict__ bias, float* __restrict__ c_out,
    float* __restrict__ u_out) {
  const int h = threadIdx.x & (H_ - 1);
  const int pg = threadIdx.x >> 7;
  const int p0 = blockIdx.x * 8 + pg * 4;
  float a0 = 0, a1 = 0, a2 = 0, a3 = 0, u0 = 0, u1 = 0, u2 = 0, u3 = 0;
  const float* xp = X + (size_t)p0 * D;
#pragma unroll 4
  for (int d = 0; d < D; ++d) {
    float wt = W[d * H_ + h];
    float wb = W[(D + d) * H_ + h];
    float x0 = xp[d], x1 = xp[D + d], x2 = xp[2 * D + d], x3 = xp[3 * D + d];
    a0 = fmaf(x0, wt, a0); u0 = fmaf(x0, wb, u0);
    a1 = fmaf(x1, wt, a1); u1 = fmaf(x1, wb, u1);
    a2 = fmaf(x2, wt, a2); u2 = fmaf(x2, wb, u2);
    a3 = fmaf(x3, wt, a3); u3 = fmaf(x3, wb, u3);
  }
  float bv = bias[h];
  c_out[(size_t)(p0 + 0) * H_ + h] = a0 - u0 + bv;
  c_out[(size_t)(p0 + 1) * H_ + h] = a1 - u1 + bv;
  c_out[(size_t)(p0 + 2) * H_ + h] = a2 - u2 + bv;
  c_out[(size_t)(p0 + 3) * H_ + h] = a3 - u3 + bv;
  u_out[(size_t)(p0 + 0) * H_ + h] = u0;
  u_out[(size_t)(p0 + 1) * H_ + h] = u1;
  u_out[(size_t)(p0 + 2) * H_ + h] = u2;
  u_out[(size_t)(p0 + 3) * H_ + h] = u3;
}

// ======================= D=3 kNN path =======================
// part: 64 rows x 4 splits; split r scans window js [r*128, r*128+128).
// Keeps top-8 -> dumps 32 values/row (+32 FINF pad) to pd.
__global__ __launch_bounds__(256) void knn3_part_kernel(
    const float4* __restrict__ pt4, float* __restrict__ pd) {
  const int tid = threadIdx.x;
  const int row_local = tid >> 2;
  const int r = tid & 3;
  const int b = blockIdx.x >> 6;
  const int i0 = (blockIdx.x & 63) * 64;
  const int gi = i0 + row_local;
  const size_t gb = (size_t)b * P_;

  float4 pi = pt4[gb + gi];
  float bd[K8];
#pragma unroll
  for (int k = 0; k < K8; ++k) bd[k] = FINF;
  float worst = FINF;

  const float4* pg = pt4 + gb + r * 128;
#pragma unroll 4
  for (int jj = 0; jj < 128; ++jj) {
    float4 v = pg[jj];
    float d = dist3(pi.x, pi.y, pi.z, v);
    int jg = r * 128 + jj;
    if (d < worst && jg != gi) {
      bool done = false;
#pragma unroll
      for (int k = 0; k < K8; ++k) {
        if (!done && bd[k] == worst) { bd[k] = d; done = true; }
      }
      worst = bd[0];
#pragma unroll
      for (int k = 1; k < K8; ++k) worst = fmaxf(worst, bd[k]);
    }
  }
  float* outp = pd + (gb + gi) * 64;
#pragma unroll
  for (int k = 0; k < K8; ++k) {
    outp[r * K8 + k] = bd[k];
    outp[32 + r * K8 + k] = FINF;  // pad so tau sees 64 values
  }
}

// compact: 4 waves; 16 rows/wave; scans one j-half (2048) in 64-lane chunks.
__global__ __launch_bounds__(256) void knn3_compact_kernel(
    const float4* __restrict__ pt4, const float* __restrict__ tau,
    float2* __restrict__ cand, int* __restrict__ cnt) {
  const int tid = threadIdx.x;
  const int lane = tid & 63;
  const int w = tid >> 6;
  const int half = blockIdx.x & 1;
  const int rgb = blockIdx.x >> 1;
  const int b = rgb >> 6;
  const int i0 = (rgb & 63) * 64;
  const size_t gb = (size_t)b * P_;
  const int r0 = i0 + w * 16;  // first row of this wave

  float xr0[16], xr1[16], xr2[16], taur[16];
  int cur[16];
#pragma unroll
  for (int r = 0; r < 16; ++r) {
    float4 p = pt4[gb + r0 + r];
    xr0[r] = p.x; xr1[r] = p.y; xr2[r] = p.z;
    taur[r] = tau[gb + r0 + r];
    cur[r] = 0;
  }

  const float4* pg = pt4 + gb + half * 2048;
  for (int ch = 0; ch < 32; ++ch) {
    float4 v = pg[ch * 64 + lane];
    int jg = half * 2048 + ch * 64 + lane;
#pragma unroll
    for (int r = 0; r < 16; ++r) {
      float d = dist3(xr0[r], xr1[r], xr2[r], v);
      bool pred = (d <= taur[r]) && (jg != r0 + r);
      unsigned long long mk = __ballot(pred);
      if (mk) {
        int n = __popcll(mk);
        int pre = __popcll(mk & ((1ull << lane) - 1ull));
        int idx = cur[r] + pre;
        if (pred && idx < CAP) {
          float2 e;
          e.x = d;
          e.y = __int_as_float(jg);
          cand[(gb + r0 + r) * (size_t)(2 * CAP) + half * CAP + idx] = e;
        }
        cur[r] += n;
      }
    }
  }
  if (lane == 0) {
#pragma unroll
    for (int r = 0; r < 16; ++r)
      cnt[(gb + r0 + r) * 2 + half] = cur[r] < CAP ? cur[r] : CAP;
  }
}

// ======================= D=128 kNN path =======================
// A1: windowed top-8 per split (MFMA dist tile); dumps 32 values per
// (row, part) to pd[row*64 + part*32 + ...].
__global__ __launch_bounds__(256) void knn_part_kernel(
    const ushort* __restrict__ Xhi, const ushort* __restrict__ Xlo,
    const float* __restrict__ sqn, float* __restrict__ pd) {
  constexpr int ROWS = 64, TJ = 64, NCH = 4;
  constexpr int PSTR = 136, DSTR = 65;
  __shared__ int4 smem_raw[3232];
  ushort* ljhi = (ushort*)smem_raw;
  ushort* ljlo = ljhi + TJ * PSTR;
  float* lsq = (float*)(ljlo + TJ * PSTR);
  float* ldist = lsq + TJ;

  const int tid = threadIdx.x;
  const int lane = tid & 63;
  const int w = tid >> 6;
  const int quad = lane >> 4;
  const int col = lane & 15;
  const int part = blockIdx.x & 1;
  const int rgb = blockIdx.x >> 1;
  const int b = rgb >> 6;
  const int i0 = (rgb & 63) * ROWS;
  const int jbase = part * (NCH * TJ);
  const size_t gb = (size_t)b * P_;

  short8 ahi[4], alo[4];
  {
    const size_t arow = (gb + i0 + w * 16 + col) * (size_t)H_;
#pragma unroll
    for (int s = 0; s < 4; ++s) {
      ahi[s] = *(const short8*)(Xhi + arow + s * 32 + quad * 8);
      alo[s] = *(const short8*)(Xlo + arow + s * 32 + quad * 8);
    }
  }

  const int srow = tid >> 2;
  const int sr = tid & 3;
  const int gi = i0 + srow;
  float bd[K8];
#pragma unroll
  for (int k = 0; k < K8; ++k) bd[k] = FINF;
  float worst = FINF;

  int prev_tb = -1;
  for (int c = 0; c < NCH; ++c) {
    const int tb = jbase + c * TJ;
    __syncthreads();
#pragma unroll
    for (int it = 0; it < 4; ++it) {
      int f = tid + it * 256;
      int p = f >> 4, q = f & 15;
      const size_t src = (gb + tb + p) * (size_t)H_ + q * 8;
      *(int4*)(ljhi + p * PSTR + q * 8) = *(const int4*)(Xhi + src);
      *(int4*)(ljlo + p * PSTR + q * 8) = *(const int4*)(Xlo + src);
    }
    if (tid < TJ) lsq[tid] = sqn[gb + tb + tid];
    if (prev_tb >= 0) {
      const float* drow = ldist + srow * DSTR + sr * 16;
#pragma unroll 4
      for (int jj = 0; jj < 16; ++jj) {
        float s = drow[jj];
        int jg = prev_tb + sr * 16 + jj;
        if (s < worst && jg != gi) {
          bool done = false;
#pragma unroll
          for (int k = 0; k < K8; ++k) {
            if (!done && bd[k] == worst) { bd[k] = s; done = true; }
          }
          worst = bd[0];
#pragma unroll
          for (int k = 1; k < K8; ++k) worst = fmaxf(worst, bd[k]);
        }
      }
    }
    __syncthreads();
    floatx4 acc[4];
#pragma unroll
    for (int t = 0; t < 4; ++t) acc[t] = (floatx4){0.f, 0.f, 0.f, 0.f};
#pragma unroll
    for (int s = 0; s < 4; ++s) {
      short8 bh[4], bl[4];
#pragma unroll
      for (int t = 0; t < 4; ++t) {
        const ushort* bp = ljhi + (t * 16 + col) * PSTR + s * 32 + quad * 8;
        bh[t] = *(const short8*)bp;
        bl[t] = *(const short8*)(bp + TJ * PSTR);
      }
#pragma unroll
      for (int t = 0; t < 4; ++t) {
        acc[t] = __builtin_amdgcn_mfma_f32_16x16x32_bf16(ahi[s], bh[t], acc[t], 0, 0, 0);
        acc[t] = __builtin_amdgcn_mfma_f32_16x16x32_bf16(ahi[s], bl[t], acc[t], 0, 0, 0);
        acc[t] = __builtin_amdgcn_mfma_f32_16x16x32_bf16(alo[s], bh[t], acc[t], 0, 0, 0);
      }
    }
#pragma unroll
    for (int t = 0; t < 4; ++t) {
      float sqv = lsq[t * 16 + col];
#pragma unroll
      for (int reg = 0; reg < 4; ++reg) {
        int rl = w * 16 + quad * 4 + reg;
        ldist[rl * DSTR + t * 16 + col] = fmaf(-2.f, acc[t][reg], sqv);
      }
    }
    prev_tb = tb;
  }
  __syncthreads();
  {
    const float* drow = ldist + srow * DSTR + sr * 16;
#pragma unroll 4
    for (int jj = 0; jj < 16; ++jj) {
      float s = drow[jj];
      int jg = prev_tb + sr * 16 + jj;
      if (s < worst && jg != gi) {
        bool done = false;
#pragma unroll
        for (int k = 0; k < K8; ++k) {
          if (!done && bd[k] == worst) { bd[k] = s; done = true; }
        }
        worst = bd[0];
#pragma unroll
        for (int k = 1; k < K8; ++k) worst = fmaxf(worst, bd[k]);
      }
    }
  }
  float* outp = pd + (gb + gi) * 64 + part * 32 + sr * K8;
#pragma unroll
  for (int k = 0; k < K8; ++k) outp[k] = bd[k];
}

// tau = exact 20th smallest of the 64 collected values (valid upper bound).
__global__ __launch_bounds__(256) void tau_kernel(const float* __restrict__ pd,
                                                  float* __restrict__ tau) {
  int row = blockIdx.x * 256 + threadIdx.x;
  float v[64];
#pragma unroll
  for (int k = 0; k < 64; ++k) v[k] = pd[(size_t)row * 64 + k];
  float m = 0.f;
  for (int sel = 0; sel < K_; ++sel) {
    m = v[0];
#pragma unroll
    for (int t = 1; t < 64; ++t) m = fminf(m, v[t]);
    bool done = false;
#pragma unroll
    for (int t = 0; t < 64; ++t) {
      if (!done && v[t] == m) { v[t] = FINF; done = true; }
    }
  }
  tau[row] = m;
}

// B: full MFMA scan + ballot compaction (D=128).
__global__ __launch_bounds__(256) void knn_compact_kernel(
    const ushort* __restrict__ Xhi, const ushort* __restrict__ Xlo,
    const float* __restrict__ sqn, const float* __restrict__ tau,
    float2* __restrict__ cand, int* __restrict__ cnt) {
  constexpr int ROWS = 64, TJ = 64, NCH = 32;
  constexpr int PSTR = 136, DSTR = 65;
  __shared__ int4 smem_raw[3232];
  ushort* ljhi = (ushort*)smem_raw;
  ushort* ljlo = ljhi + TJ * PSTR;
  float* lsq = (float*)(ljlo + TJ * PSTR);
  float* ldist = lsq + TJ;

  const int tid = threadIdx.x;
  const int lane = tid & 63;
  const int w = tid >> 6;
  const int quad = lane >> 4;
  const int col = lane & 15;
  const int half = blockIdx.x & 1;
  const int rgb = blockIdx.x >> 1;
  const int b = rgb >> 6;
  const int i0 = (rgb & 63) * ROWS;
  const int jbase = half * (NCH * TJ);
  const size_t gb = (size_t)b * P_;

  short8 ahi[4], alo[4];
  {
    const size_t arow = (gb + i0 + w * 16 + col) * (size_t)H_;
#pragma unroll
    for (int s = 0; s < 4; ++s) {
      ahi[s] = *(const short8*)(Xhi + arow + s * 32 + quad * 8);
      alo[s] = *(const short8*)(Xlo + arow + s * 32 + quad * 8);
    }
  }

  float taur[16];
  int cur[16];
#pragma unroll
  for (int r = 0; r < 16; ++r) {
    taur[r] = tau[gb + i0 + w * 16 + r];
    cur[r] = 0;
  }

  int prev_tb = -1;
  for (int c = 0; c < NCH; ++c) {
    const int tb = jbase + c * TJ;
    __syncthreads();
#pragma unroll
    for (int it = 0; it < 4; ++it) {
      int f = tid + it * 256;
      int p = f >> 4, q = f & 15;
      const size_t src = (gb + tb + p) * (size_t)H_ + q * 8;
      *(int4*)(ljhi + p * PSTR + q * 8) = *(const int4*)(Xhi + src);
      *(int4*)(ljlo + p * PSTR + q * 8) = *(const int4*)(Xlo + src);
    }
    if (tid < TJ) lsq[tid] = sqn[gb + tb + tid];
    if (prev_tb >= 0) {
#pragma unroll
      for (int r = 0; r < 16; ++r) {
        float d = ldist[(w * 16 + r) * DSTR + lane];
        int jg = prev_tb + lane;
        bool pred = (d <= taur[r]) && (jg != i0 + w * 16 + r);
        unsigned long long mk = __ballot(pred);
        if (mk) {
          int n = __popcll(mk);
          int pre = __popcll(mk & ((1ull << lane) - 1ull));
          int idx = cur[r] + pre;
          if (pred && idx < CAP) {
            float2 e;
            e.x = d;
            e.y = __int_as_float(jg);
            cand[(gb + i0 + w * 16 + r) * (size_t)(2 * CAP) + half * CAP + idx] = e;
          }
          cur[r] += n;
        }
      }
    }
    __syncthreads();
    floatx4 acc[4];
#pragma unroll
    for (int t = 0; t < 4; ++t) acc[t] = (floatx4){0.f, 0.f, 0.f, 0.f};
#pragma unroll
    for (int s = 0; s < 4; ++s) {
      short8 bh[4], bl[4];
#pragma unroll
      for (int t = 0; t < 4; ++t) {
        const ushort* bp = ljhi + (t * 16 + col) * PSTR + s * 32 + quad * 8;
        bh[t] = *(const short8*)bp;
        bl[t] = *(const short8*)(bp + TJ * PSTR);
      }
#pragma unroll
      for (int t = 0; t < 4; ++t) {
        acc[t] = __builtin_amdgcn_mfma_f32_16x16x32_bf16(ahi[s], bh[t], acc[t], 0, 0, 0);
        acc[t] = __builtin_amdgcn_mfma_f32_16x16x32_bf16(ahi[s], bl[t], acc[t], 0, 0, 0);
        acc[t] = __builtin_amdgcn_mfma_f32_16x16x32_bf16(alo[s], bh[t], acc[t], 0, 0, 0);
      }
    }
#pragma unroll
    for (int t = 0; t < 4; ++t) {
      float sqv = lsq[t * 16 + col];
#pragma unroll
      for (int reg = 0; reg < 4; ++reg) {
        int rl = w * 16 + quad * 4 + reg;
        ldist[rl * DSTR + t * 16 + col] = fmaf(-2.f, acc[t][reg], sqv);
      }
    }
    prev_tb = tb;
  }
  __syncthreads();
#pragma unroll
  for (int r = 0; r < 16; ++r) {
    float d = ldist[(w * 16 + r) * DSTR + lane];
    int jg = prev_tb + lane;
    bool pred = (d <= taur[r]) && (jg != i0 + w * 16 + r);
    unsigned long long mk = __ballot(pred);
    if (mk) {
      int n = __popcll(mk);
      int pre = __popcll(mk & ((1ull << lane) - 1ull));
      int idx = cur[r] + pre;
      if (pred && idx < CAP) {
        float2 e;
        e.x = d;
        e.y = __int_as_float(jg);
        cand[(gb + i0 + w * 16 + r) * (size_t)(2 * CAP) + half * CAP + idx] = e;
      }
      cur[r] += n;
    }
  }
  if (lane == 0) {
#pragma unroll
    for (int r = 0; r < 16; ++r) {
      cnt[(gb + i0 + w * 16 + r) * 2 + half] = cur[r] < CAP ? cur[r] : CAP;
    }
  }
}

// C: exact top-20 of survivors (one wave per row).
__global__ __launch_bounds__(256) void knn_select_kernel(
    const float2* __restrict__ cand, const int* __restrict__ cnt,
    int* __restrict__ nbr) {
  const int w = threadIdx.x >> 6;
  const int lane = threadIdx.x & 63;
  const int row = blockIdx.x * 4 + w;
  const int c0 = cnt[row * 2], c1 = cnt[row * 2 + 1];
  const int ctot = c0 + c1;
  float d[6];
  int j[6];
#pragma unroll
  for (int s = 0; s < 6; ++s) {
    int m = s * 64 + lane;
    bool valid = m < ctot;
    int addr = (m < c0) ? m : (CAP + m - c0);
    if (!valid) addr = 0;
    float2 e = cand[(size_t)row * (2 * CAP) + addr];
    d[s] = valid ? e.x : FINF;
    j[s] = __float_as_int(e.y);
  }
  int* outp = nbr + (size_t)row * K_;
  for (int round = 0; round < K_; ++round) {
    float bm = d[0];
    int bs = 0;
#pragma unroll
    for (int s = 1; s < 6; ++s) {
      if (d[s] < bm) { bm = d[s]; bs = s; }
    }
    int id = (lane << 3) | bs;
#pragma unroll
    for (int off = 1; off < 64; off <<= 1) {
      float od = __shfl_xor(bm, off);
      int oid = __shfl_xor(id, off);
      if (od < bm || (od == bm && oid < id)) { bm = od; id = oid; }
    }
    int owner = id >> 3, os = id & 7;
    if (lane == owner) {
      int jv = 0;
#pragma unroll
      for (int s = 0; s < 6; ++s) {
        if (s == os) { jv = j[s]; d[s] = FINF; }
      }
      outp[round] = jv;
    }
  }
}

// ---------------- gather + max aggregation ----------------
__global__ __launch_bounds__(256) void aggr_kernel(const float* __restrict__ c,
                                                   const float* __restrict__ u,
                                                   const int* __restrict__ nbr,
                                                   float* __restrict__ out) {
  int g = blockIdx.x * 256 + threadIdx.x;
  int h = g & (H_ - 1);
  int i = g >> 7;
  int b = i >> 12;
  const int* nb = nbr + (size_t)i * K_;
  float ci = c[g];
  float m = 0.f;
#pragma unroll
  for (int k = 0; k < K_; ++k) {
    int j = nb[k];
    float v = ci + u[(size_t)(b * P_ + j) * H_ + h];
    m = fmaxf(m, v);
  }
  out[g] = m;
}

// ---------------- head: mean pool + MLP ----------------
__global__ void zero_kernel(float* __restrict__ gsum) {
  gsum[threadIdx.x + blockIdx.x * 256] = 0.f;
}

__global__ __launch_bounds__(128) void pool_kernel(const float* __restrict__ hf,
                                                   float* __restrict__ gsum) {
  constexpr int CHUNK = 64;
  int blk = blockIdx.x;
  int b = blk / (P_ / CHUNK);
  int chunk = blk % (P_ / CHUNK);
  int h = threadIdx.x;
  int base = b * P_ + chunk * CHUNK;
  float acc = 0.f;
#pragma unroll 4
  for (int p = 0; p < CHUNK; ++p) acc += hf[(size_t)(base + p) * H_ + h];
  atomicAdd(&gsum[b * H_ + h], acc);
}

__global__ __launch_bounds__(128) void head_kernel(
    const float* __restrict__ gsum, const float* __restrict__ W4,
    const float* __restrict__ b4, const float* __restrict__ W5,
    const float* __restrict__ b5, float* __restrict__ out) {
  int b = blockIdx.x, h = threadIdx.x;
  __shared__ float g[H_];
  __shared__ float t[H_];
  g[h] = gsum[b * H_ + h] * (1.0f / P_);
  __syncthreads();
  float acc = b4[h];
#pragma unroll 4
  for (int d = 0; d < H_; ++d) acc = fmaf(g[d], W4[d * H_ + h], acc);
  t[h] = fmaxf(acc, 0.f);
  __syncthreads();
  if (h < 3) {
    float o = b5[h];
#pragma unroll 4
    for (int d = 0; d < H_; ++d) o = fmaf(t[d], W5[d * 3 + h], o);
    out[b * 3 + h] = o;
  }
}

extern "C" void kernel_launch(void* const* d_in, const int* in_sizes, int n_in,
                              void* d_out, int out_size, void* d_ws,
                              size_t ws_size, hipStream_t stream) {
  const float* x  = (const float*)d_in[0];
  const float* W1 = (const float*)d_in[1];
  const float* b1 = (const float*)d_in[2];
  const float* W2 = (const float*)d_in[3];
  const float* b2 = (const float*)d_in[4];
  const float* W3 = (const float*)d_in[5];
  const float* b3 = (const float*)d_in[6];
  const float* W4 = (const float*)d_in[7];
  const float* b4 = (const float*)d_in[8];
  const float* W5 = (const float*)d_in[9];
  const float* b5 = (const float*)d_in[10];
  float* out = (float*)d_out;

  char* ws = (char*)d_ws;
  const size_t NF = (size_t)B_ * P_ * H_;   // 4,194,304
  const size_t NP_ = (size_t)B_ * P_;       // 32768
  float*  bufA = (float*)ws;  ws += NF * 4;
  float*  bufB = (float*)ws;  ws += NF * 4;
  float*  bufU = (float*)ws;  ws += NF * 4;
  ushort* xhi  = (ushort*)ws; ws += NF * 2;
  ushort* xlo  = (ushort*)ws; ws += NF * 2;
  float*  sqn  = (float*)ws;  ws += NP_ * 4;
  int*    nbr  = (int*)ws;    ws += NP_ * K_ * 4;
  float*  gsum = (float*)ws;  ws += (size_t)B_ * H_ * 4;
  float*  pd   = (float*)ws;  ws += NP_ * 64 * 4;
  float*  tau  = (float*)ws;  ws += NP_ * 4;
  int*    cnt  = (int*)ws;    ws += NP_ * 2 * 4;
  float4* pt4  = (float4*)ws; ws += NP_ * 16;
  float2* cand = (float2*)ws; ws += NP_ * (size_t)(2 * CAP) * 8;

  const int NP = B_ * P_;
  dim3 blk256(256), blk128(128);

  // ---- layer 1 (D=3)
  pack4_kernel<<<NP / 256, blk256, 0, stream>>>(x, pt4);
  feat_kernel<3><<<NP / 8, blk256, 0, stream>>>(x, W1, b1, bufA, bufU);
  knn3_part_kernel<<<B_ * 64, blk256, 0, stream>>>(pt4, pd);
  tau_kernel<<<NP / 256, blk256, 0, stream>>>(pd, tau);
  knn3_compact_kernel<<<B_ * 64 * 2, blk256, 0, stream>>>(pt4, tau, cand, cnt);
  knn_select_kernel<<<NP / 4, blk256, 0, stream>>>(cand, cnt, nbr);
  aggr_kernel<<<(NP * H_) / 256, blk256, 0, stream>>>(bufA, bufU, nbr, bufA);

  // ---- layer 2 (D=128), X = bufA
  split_kernel<<<(int)(NF / 4 / 256), blk256, 0, stream>>>(bufA, xhi, xlo);
  sq_kernel<128><<<NP / 256, blk256, 0, stream>>>(bufA, sqn);
  feat_kernel<128><<<NP / 8, blk256, 0, stream>>>(bufA, W2, b2, bufB, bufU);
  knn_part_kernel<<<B_ * 64 * 2, blk256, 0, stream>>>(xhi, xlo, sqn, pd);
  tau_kernel<<<NP / 256, blk256, 0, stream>>>(pd, tau);
  knn_compact_kernel<<<B_ * 64 * 2, blk256, 0, stream>>>(xhi, xlo, sqn, tau, cand, cnt);
  knn_select_kernel<<<NP / 4, blk256, 0, stream>>>(cand, cnt, nbr);
  aggr_kernel<<<(NP * H_) / 256, blk256, 0, stream>>>(bufB, bufU, nbr, bufB);

  // ---- layer 3 (D=128), X = bufB
  split_kernel<<<(int)(NF / 4 / 256), blk256, 0, stream>>>(bufB, xhi, xlo);
  sq_kernel<128><<<NP / 256, blk256, 0, stream>>>(bufB, sqn);
  feat_kernel<128><<<NP / 8, blk256, 0, stream>>>(bufB, W3, b3, bufA, bufU);
  knn_part_kernel<<<B_ * 64 * 2, blk256, 0, stream>>>(xhi, xlo, sqn, pd);
  tau_kernel<<<NP / 256, blk256, 0, stream>>>(pd, tau);
  knn_compact_kernel<<<B_ * 64 * 2, blk256, 0, stream>>>(xhi, xlo, sqn, tau, cand, cnt);
  knn_select_kernel<<<NP / 4, blk256, 0, stream>>>(cand, cnt, nbr);
  aggr_kernel<<<(NP * H_) / 256, blk256, 0, stream>>>(bufA, bufU, nbr, bufA);

  // ---- head
  zero_kernel<<<(B_ * H_) / 256, blk256, 0, stream>>>(gsum);
  pool_kernel<<<B_ * (P_ / 64), blk128, 0, stream>>>(bufA, gsum);
  head_kernel<<<B_, blk128, 0, stream>>>(gsum, W4, b4, W5, b5, out);
}

// Round 5
// 1396.865 us; speedup vs baseline: 3.1696x; 1.0258x over previous
//
#include <hip/hip_runtime.h>
#include <hip/hip_bf16.h>

// DGCNN: B=8, P=4096, K=20, H=128.
// EdgeConv: relu([xi, xj-xi]@W + b) == relu(c_i + u_j).
// kNN: gram via 32x32x16 MFMA split-bf16 (hh+hl+lh); selection via threshold
// compaction: tau = 20th of >=20 distinct window values (upper bound of true
// 20th) -> ballot-compact d<=tau straight from MFMA C-layout registers ->
// exact top-20 of survivors. Part & compact share bit-identical gram code.

static constexpr int B_ = 8, P_ = 4096, K_ = 20, H_ = 128;
static constexpr float FINF = 3.0e38f;
static constexpr int CAPQ = 96;  // survivors per row per j-quarter (E~42)
static constexpr int K12 = 12;   // per-split kept values for tau bound

typedef __attribute__((ext_vector_type(8))) short short8;
typedef __attribute__((ext_vector_type(16))) float floatx16;

__device__ __forceinline__ float dist3(float x0, float x1, float x2,
                                       const float4& v) {
  // MUST be bit-identical between part and compact kernels.
  return fmaf(-2.f, fmaf(x0, v.x, fmaf(x1, v.y, x2 * v.z)), v.w);
}

// ---------------- squared norms (D=128 layers) ----------------
template <int D>
__global__ __launch_bounds__(256) void sq_kernel(const float* __restrict__ X,
                                                 float* __restrict__ sqn) {
  int p = blockIdx.x * 256 + threadIdx.x;
  const float* row = X + (size_t)p * D;
  float s = 0.f;
#pragma unroll
  for (int d = 0; d < D; ++d) s = fmaf(row[d], row[d], s);
  sqn[p] = s;
}

// ---------------- pack (x,y,z,|x|^2) for layer-1 ----------------
__global__ __launch_bounds__(256) void pack4_kernel(const float* __restrict__ X,
                                                    float4* __restrict__ pt4) {
  int p = blockIdx.x * 256 + threadIdx.x;
  const float* row = X + (size_t)p * 3;
  float4 v;
  v.x = row[0]; v.y = row[1]; v.z = row[2];
  v.w = fmaf(v.x, v.x, fmaf(v.y, v.y, v.z * v.z));
  pt4[p] = v;
}

// ---------------- f32 -> bf16 hi/lo split ----------------
__global__ __launch_bounds__(256) void split_kernel(const float* __restrict__ X,
                                                    ushort* __restrict__ hi,
                                                    ushort* __restrict__ lo) {
  int g = (blockIdx.x * 256 + threadIdx.x) * 4;
  float4 v = *(const float4*)(X + g);
  ushort4 h, l;
#define CVT(c)                                        \
  {                                                   \
    __hip_bfloat16 hb = __float2bfloat16(v.c);        \
    float hf = __bfloat162float(hb);                  \
    __hip_bfloat16 lb = __float2bfloat16(v.c - hf);   \
    h.c = *(ushort*)&hb;                              \
    l.c = *(ushort*)&lb;                              \
  }
  CVT(x) CVT(y) CVT(z) CVT(w)
#undef CVT
  *(ushort4*)(hi + g) = h;
  *(ushort4*)(lo + g) = l;
}

// ---------------- c_i / u_j GEMMs ----------------
template <int D>
__global__ __launch_bounds__(256) void feat_kernel(
    const float* __restrict__ X, const float* __restrict__ W,
    const float* __restrict__ bias, float* __restrict__ c_out,
    float* __restrict__ u_out) {
  const int h = threadIdx.x & (H_ - 1);
  const int pg = threadIdx.x >> 7;
  const int p0 = blockIdx.x * 8 + pg * 4;
  float a0 = 0, a1 = 0, a2 = 0, a3 = 0, u0 = 0, u1 = 0, u2 = 0, u3 = 0;
  const float* xp = X + (size_t)p0 * D;
#pragma unroll 4
  for (int d = 0; d < D; ++d) {
    float wt = W[d * H_ + h];
    float wb = W[(D + d) * H_ + h];
    float x0 = xp[d], x1 = xp[D + d], x2 = xp[2 * D + d], x3 = xp[3 * D + d];
    a0 = fmaf(x0, wt, a0); u0 = fmaf(x0, wb, u0);
    a1 = fmaf(x1, wt, a1); u1 = fmaf(x1, wb, u1);
    a2 = fmaf(x2, wt, a2); u2 = fmaf(x2, wb, u2);
    a3 = fmaf(x3, wt, a3); u3 = fmaf(x3, wb, u3);
  }
  float bv = bias[h];
  c_out[(size_t)(p0 + 0) * H_ + h] = a0 - u0 + bv;
  c_out[(size_t)(p0 + 1) * H_ + h] = a1 - u1 + bv;
  c_out[(size_t)(p0 + 2) * H_ + h] = a2 - u2 + bv;
  c_out[(size_t)(p0 + 3) * H_ + h] = a3 - u3 + bv;
  u_out[(size_t)(p0 + 0) * H_ + h] = u0;
  u_out[(size_t)(p0 + 1) * H_ + h] = u1;
  u_out[(size_t)(p0 + 2) * H_ + h] = u2;
  u_out[(size_t)(p0 + 3) * H_ + h] = u3;
}

// =============== shared gram machinery (D=128) ===============
// LDS j-tile layout: point p (0..63), feature-chunk q (0..15, 8 ushorts):
//   byte offset = p*256 + ((q ^ (p&15)) << 4); lo buffer at +16384.
// Coalesced global reads; conflict-free ds_write_b128 / ds_read_b128.
__device__ __forceinline__ void stage_chunk(const ushort* __restrict__ Xhi,
                                            const ushort* __restrict__ Xlo,
                                            char* lds, size_t grow, int tid) {
#pragma unroll
  for (int it = 0; it < 4; ++it) {
    int f = tid + it * 256;
    int p = f >> 4, q = f & 15;
    const size_t src = (grow + p) * (size_t)H_ + q * 8;
    int off = p * 256 + ((q ^ (p & 15)) << 4);
    *(int4*)(lds + off) = *(const int4*)(Xhi + src);
    *(int4*)(lds + 16384 + off) = *(const int4*)(Xlo + src);
  }
}

// A fragment: rows rowbase + (lane&31), feats k = s*16 + (lane>>5)*8 .. +8
__device__ __forceinline__ void load_afrag(const ushort* __restrict__ X,
                                           size_t rowbase, int lane,
                                           short8* a) {
  const size_t r = (rowbase + (lane & 31)) * (size_t)H_ + (lane >> 5) * 8;
#pragma unroll
  for (int s = 0; s < 8; ++s) a[s] = *(const short8*)(X + r + s * 16);
}

// 32x32 gram tile: rows = wave's 32, j = jh*32..+32 of the staged chunk.
// MFMA order (hh, hl, lh per k-step) MUST stay identical everywhere.
__device__ __forceinline__ floatx16 gram32(const char* lds, const short8* ahi,
                                           const short8* alo, int jh,
                                           int lane) {
  floatx16 acc;
#pragma unroll
  for (int i = 0; i < 16; ++i) acc[i] = 0.f;
  const int base = (jh * 32 + (lane & 31)) * 256;
  const int kh = lane >> 5;
  const int x = lane & 15;
#pragma unroll
  for (int s = 0; s < 8; ++s) {
    const int off = base + (((s * 2 + kh) ^ x) << 4);
    short8 bh = *(const short8*)(lds + off);
    short8 bl = *(const short8*)(lds + 16384 + off);
    acc = __builtin_amdgcn_mfma_f32_32x32x16_bf16(ahi[s], bh, acc, 0, 0, 0);
    acc = __builtin_amdgcn_mfma_f32_32x32x16_bf16(ahi[s], bl, acc, 0, 0, 0);
    acc = __builtin_amdgcn_mfma_f32_32x32x16_bf16(alo[s], bh, acc, 0, 0, 0);
  }
  return acc;
}

// =============== D=128 part: window [0,512) -> top-12 x 4 splits ===========
__global__ __launch_bounds__(256) void knn_part_kernel(
    const ushort* __restrict__ Xhi, const ushort* __restrict__ Xlo,
    const float* __restrict__ sqn, float* __restrict__ pd) {
  __shared__ int4 lds4[2048];        // 32 KB staging
  __shared__ float ldist[64 * 65];   // dist tile
  char* lds = (char*)lds4;

  const int tid = threadIdx.x;
  const int lane = tid & 63;
  const int w = tid >> 6;
  const int rh = w >> 1, jh = w & 1;
  const int b = blockIdx.x >> 6;
  const int i0 = (blockIdx.x & 63) * 64;
  const size_t gb = (size_t)b * P_;

  short8 ahi[8], alo[8];
  load_afrag(Xhi, gb + i0 + rh * 32, lane, ahi);
  load_afrag(Xlo, gb + i0 + rh * 32, lane, alo);
  const int rowb = rh * 32 + 4 * (lane >> 5);
  const int jcol = jh * 32 + (lane & 31);

  const int srow = tid >> 2;   // selection: 4 threads per row
  const int sr = tid & 3;
  const int gi = i0 + srow;
  float bd[K12];
#pragma unroll
  for (int k = 0; k < K12; ++k) bd[k] = FINF;
  float worst = FINF;

  for (int ch = 0; ch < 8; ++ch) {
    const int tb = ch * 64;
    __syncthreads();
    stage_chunk(Xhi, Xlo, lds, gb + tb, tid);
    __syncthreads();
    float sqv = sqn[gb + tb + jcol];
    floatx16 acc = gram32(lds, ahi, alo, jh, lane);
#pragma unroll
    for (int g = 0; g < 16; ++g) {
      ldist[(rowb + (g & 3) + 8 * (g >> 2)) * 65 + jcol] =
          fmaf(-2.f, acc[g], sqv);
    }
    __syncthreads();
    const float* drow = ldist + srow * 65 + sr * 16;
#pragma unroll 4
    for (int jj = 0; jj < 16; ++jj) {
      float s = drow[jj];
      int jg = tb + sr * 16 + jj;
      if (s < worst && jg != gi) {
        bool done = false;
#pragma unroll
        for (int k = 0; k < K12; ++k) {
          if (!done && bd[k] == worst) { bd[k] = s; done = true; }
        }
        worst = bd[0];
#pragma unroll
        for (int k = 1; k < K12; ++k) worst = fmaxf(worst, bd[k]);
      }
    }
  }
  float* outp = pd + (gb + gi) * 64;
#pragma unroll
  for (int k = 0; k < K12; ++k) outp[sr * K12 + k] = bd[k];
#pragma unroll
  for (int k = 0; k < 4; ++k) outp[48 + sr * 4 + k] = FINF;  // pad to 64
}

// tau = exact 20th smallest of the 64 collected values (valid upper bound).
__global__ __launch_bounds__(256) void tau_kernel(const float* __restrict__ pd,
                                                  float* __restrict__ tau) {
  int row = blockIdx.x * 256 + threadIdx.x;
  float v[64];
#pragma unroll
  for (int k = 0; k < 64; ++k) v[k] = pd[(size_t)row * 64 + k];
  float m = 0.f;
  for (int sel = 0; sel < K_; ++sel) {
    m = v[0];
#pragma unroll
    for (int t = 1; t < 64; ++t) m = fminf(m, v[t]);
    bool done = false;
#pragma unroll
    for (int t = 0; t < 64; ++t) {
      if (!done && v[t] == m) { v[t] = FINF; done = true; }
    }
  }
  tau[row] = m;
}

// =============== D=128 compact: register-space ballot compaction ===========
// grid = B*64*2 (j-halves); block = 64 rows x 2048 j; cand quarter = half*2+jh
__global__ __launch_bounds__(256) void knn_compact_kernel(
    const ushort* __restrict__ Xhi, const ushort* __restrict__ Xlo,
    const float* __restrict__ sqn, const float* __restrict__ tau,
    float2* __restrict__ cand, int* __restrict__ cnt) {
  __shared__ int4 lds4[2048];  // 32 KB staging only
  char* lds = (char*)lds4;

  const int tid = threadIdx.x;
  const int lane = tid & 63;
  const int w = tid >> 6;
  const int rh = w >> 1, jh = w & 1;
  const int half = blockIdx.x & 1;
  const int rgb = blockIdx.x >> 1;
  const int b = rgb >> 6;
  const int i0 = (rgb & 63) * 64;
  const size_t gb = (size_t)b * P_;
  const int quar = half * 2 + jh;

  short8 ahi[8], alo[8];
  load_afrag(Xhi, gb + i0 + rh * 32, lane, ahi);
  load_afrag(Xlo, gb + i0 + rh * 32, lane, alo);

  const int rowb = i0 + rh * 32 + 4 * (lane >> 5);
  float taur[16];
  int cur[16];
#pragma unroll
  for (int g = 0; g < 16; ++g) {
    taur[g] = tau[gb + rowb + (g & 3) + 8 * (g >> 2)];
    cur[g] = 0;
  }
  const unsigned lmask = (1u << (lane & 31)) - 1u;
  const int jcol = jh * 32 + (lane & 31);
  const int jbase = half * 2048;

  for (int c = 0; c < 32; ++c) {
    const int tb = jbase + c * 64;
    __syncthreads();
    stage_chunk(Xhi, Xlo, lds, gb + tb, tid);
    __syncthreads();
    float sqv = sqn[gb + tb + jcol];
    floatx16 acc = gram32(lds, ahi, alo, jh, lane);
    const int jg = tb + jcol;
#pragma unroll
    for (int g = 0; g < 16; ++g) {
      const int row = rowb + (g & 3) + 8 * (g >> 2);
      float d = fmaf(-2.f, acc[g], sqv);
      bool pred = (d <= taur[g]) && (jg != row);
      unsigned long long mk = __ballot(pred);
      unsigned seg = (lane >= 32) ? (unsigned)(mk >> 32) : (unsigned)mk;
      int idx = cur[g] + __popc(seg & lmask);
      if (pred && idx < CAPQ) {
        float2 e;
        e.x = d;
        e.y = __int_as_float(jg);
        cand[(gb + row) * (size_t)(4 * CAPQ) + quar * CAPQ + idx] = e;
      }
      cur[g] += __popc(seg);
    }
  }
  if ((lane & 31) == 0) {
#pragma unroll
    for (int g = 0; g < 16; ++g) {
      int row = rowb + (g & 3) + 8 * (g >> 2);
      cnt[(gb + row) * 4 + quar] = cur[g] < CAPQ ? cur[g] : CAPQ;
    }
  }
}

// ======================= D=3 kNN path =======================
__global__ __launch_bounds__(256) void knn3_part_kernel(
    const float4* __restrict__ pt4, float* __restrict__ pd) {
  const int tid = threadIdx.x;
  const int row_local = tid >> 2;
  const int r = tid & 3;
  const int b = blockIdx.x >> 6;
  const int i0 = (blockIdx.x & 63) * 64;
  const int gi = i0 + row_local;
  const size_t gb = (size_t)b * P_;

  float4 pi = pt4[gb + gi];
  float bd[8];
#pragma unroll
  for (int k = 0; k < 8; ++k) bd[k] = FINF;
  float worst = FINF;

  const float4* pg = pt4 + gb + r * 128;
#pragma unroll 4
  for (int jj = 0; jj < 128; ++jj) {
    float4 v = pg[jj];
    float d = dist3(pi.x, pi.y, pi.z, v);
    int jg = r * 128 + jj;
    if (d < worst && jg != gi) {
      bool done = false;
#pragma unroll
      for (int k = 0; k < 8; ++k) {
        if (!done && bd[k] == worst) { bd[k] = d; done = true; }
      }
      worst = bd[0];
#pragma unroll
      for (int k = 1; k < 8; ++k) worst = fmaxf(worst, bd[k]);
    }
  }
  float* outp = pd + (gb + gi) * 64;
#pragma unroll
  for (int k = 0; k < 8; ++k) {
    outp[r * 8 + k] = bd[k];
    outp[32 + r * 8 + k] = FINF;  // pad so tau sees 64 values
  }
}

// quarter-based: grid B*64*4; each block scans 1024 j for its 64 rows.
__global__ __launch_bounds__(256) void knn3_compact_kernel(
    const float4* __restrict__ pt4, const float* __restrict__ tau,
    float2* __restrict__ cand, int* __restrict__ cnt) {
  const int tid = threadIdx.x;
  const int lane = tid & 63;
  const int w = tid >> 6;
  const int quar = blockIdx.x & 3;
  const int rgb = blockIdx.x >> 2;
  const int b = rgb >> 6;
  const int i0 = (rgb & 63) * 64;
  const size_t gb = (size_t)b * P_;
  const int r0 = i0 + w * 16;

  float xr0[16], xr1[16], xr2[16], taur[16];
  int cur[16];
#pragma unroll
  for (int r = 0; r < 16; ++r) {
    float4 p = pt4[gb + r0 + r];
    xr0[r] = p.x; xr1[r] = p.y; xr2[r] = p.z;
    taur[r] = tau[gb + r0 + r];
    cur[r] = 0;
  }

  const float4* pg = pt4 + gb + quar * 1024;
  for (int ch = 0; ch < 16; ++ch) {
    float4 v = pg[ch * 64 + lane];
    int jg = quar * 1024 + ch * 64 + lane;
#pragma unroll
    for (int r = 0; r < 16; ++r) {
      float d = dist3(xr0[r], xr1[r], xr2[r], v);
      bool pred = (d <= taur[r]) && (jg != r0 + r);
      unsigned long long mk = __ballot(pred);
      if (mk) {
        int n = __popcll(mk);
        int pre = __popcll(mk & ((1ull << lane) - 1ull));
        int idx = cur[r] + pre;
        if (pred && idx < CAPQ) {
          float2 e;
          e.x = d;
          e.y = __int_as_float(jg);
          cand[(gb + r0 + r) * (size_t)(4 * CAPQ) + quar * CAPQ + idx] = e;
        }
        cur[r] += n;
      }
    }
  }
  if (lane == 0) {
#pragma unroll
    for (int r = 0; r < 16; ++r)
      cnt[(gb + r0 + r) * 4 + quar] = cur[r] < CAPQ ? cur[r] : CAPQ;
  }
}

// C: exact top-20 of survivors (one wave per row), 4 quarter-buffers.
__global__ __launch_bounds__(256) void knn_select_kernel(
    const float2* __restrict__ cand, const int* __restrict__ cnt,
    int* __restrict__ nbr) {
  const int w = threadIdx.x >> 6;
  const int lane = threadIdx.x & 63;
  const int row = blockIdx.x * 4 + w;
  const int c0 = cnt[row * 4], c1 = cnt[row * 4 + 1];
  const int c2 = cnt[row * 4 + 2], c3 = cnt[row * 4 + 3];
  const int b1 = c0 + c1, b2 = b1 + c2, ctot = b2 + c3;
  float d[6];
  int j[6];
#pragma unroll
  for (int s = 0; s < 6; ++s) {
    int m = s * 64 + lane;
    bool valid = m < ctot;
    int addr = m;
    if (m >= c0) addr = CAPQ + (m - c0);
    if (m >= b1) addr = 2 * CAPQ + (m - b1);
    if (m >= b2) addr = 3 * CAPQ + (m - b2);
    if (!valid) addr = 0;
    float2 e = cand[(size_t)row * (4 * CAPQ) + addr];
    d[s] = valid ? e.x : FINF;
    j[s] = __float_as_int(e.y);
  }
  int* outp = nbr + (size_t)row * K_;
  for (int round = 0; round < K_; ++round) {
    float bm = d[0];
    int bs = 0;
#pragma unroll
    for (int s = 1; s < 6; ++s) {
      if (d[s] < bm) { bm = d[s]; bs = s; }
    }
    int id = (lane << 3) | bs;
#pragma unroll
    for (int off = 1; off < 64; off <<= 1) {
      float od = __shfl_xor(bm, off);
      int oid = __shfl_xor(id, off);
      if (od < bm || (od == bm && oid < id)) { bm = od; id = oid; }
    }
    int owner = id >> 3, os = id & 7;
    if (lane == owner) {
      int jv = 0;
#pragma unroll
      for (int s = 0; s < 6; ++s) {
        if (s == os) { jv = j[s]; d[s] = FINF; }
      }
      outp[round] = jv;
    }
  }
}

// ---------------- gather + max aggregation ----------------
__global__ __launch_bounds__(256) void aggr_kernel(const float* __restrict__ c,
                                                   const float* __restrict__ u,
                                                   const int* __restrict__ nbr,
                                                   float* __restrict__ out) {
  int g = blockIdx.x * 256 + threadIdx.x;
  int h = g & (H_ - 1);
  int i = g >> 7;
  int b = i >> 12;
  const int* nb = nbr + (size_t)i * K_;
  float ci = c[g];
  float m = 0.f;
#pragma unroll
  for (int k = 0; k < K_; ++k) {
    int j = nb[k];
    float v = ci + u[(size_t)(b * P_ + j) * H_ + h];
    m = fmaxf(m, v);
  }
  out[g] = m;
}

// ---------------- head: mean pool + MLP ----------------
__global__ void zero_kernel(float* __restrict__ gsum) {
  gsum[threadIdx.x + blockIdx.x * 256] = 0.f;
}

__global__ __launch_bounds__(128) void pool_kernel(const float* __restrict__ hf,
                                                   float* __restrict__ gsum) {
  constexpr int CHUNK = 64;
  int blk = blockIdx.x;
  int b = blk / (P_ / CHUNK);
  int chunk = blk % (P_ / CHUNK);
  int h = threadIdx.x;
  int base = b * P_ + chunk * CHUNK;
  float acc = 0.f;
#pragma unroll 4
  for (int p = 0; p < CHUNK; ++p) acc += hf[(size_t)(base + p) * H_ + h];
  atomicAdd(&gsum[b * H_ + h], acc);
}

__global__ __launch_bounds__(128) void head_kernel(
    const float* __restrict__ gsum, const float* __restrict__ W4,
    const float* __restrict__ b4, const float* __restrict__ W5,
    const float* __restrict__ b5, float* __restrict__ out) {
  int b = blockIdx.x, h = threadIdx.x;
  __shared__ float g[H_];
  __shared__ float t[H_];
  g[h] = gsum[b * H_ + h] * (1.0f / P_);
  __syncthreads();
  float acc = b4[h];
#pragma unroll 4
  for (int d = 0; d < H_; ++d) acc = fmaf(g[d], W4[d * H_ + h], acc);
  t[h] = fmaxf(acc, 0.f);
  __syncthreads();
  if (h < 3) {
    float o = b5[h];
#pragma unroll 4
    for (int d = 0; d < H_; ++d) o = fmaf(t[d], W5[d * 3 + h], o);
    out[b * 3 + h] = o;
  }
}

extern "C" void kernel_launch(void* const* d_in, const int* in_sizes, int n_in,
                              void* d_out, int out_size, void* d_ws,
                              size_t ws_size, hipStream_t stream) {
  const float* x  = (const float*)d_in[0];
  const float* W1 = (const float*)d_in[1];
  const float* b1 = (const float*)d_in[2];
  const float* W2 = (const float*)d_in[3];
  const float* b2 = (const float*)d_in[4];
  const float* W3 = (const float*)d_in[5];
  const float* b3 = (const float*)d_in[6];
  const float* W4 = (const float*)d_in[7];
  const float* b4 = (const float*)d_in[8];
  const float* W5 = (const float*)d_in[9];
  const float* b5 = (const float*)d_in[10];
  float* out = (float*)d_out;

  char* ws = (char*)d_ws;
  const size_t NF = (size_t)B_ * P_ * H_;   // 4,194,304
  const size_t NP_ = (size_t)B_ * P_;       // 32768
  float*  bufA = (float*)ws;  ws += NF * 4;
  float*  bufB = (float*)ws;  ws += NF * 4;
  float*  bufU = (float*)ws;  ws += NF * 4;
  ushort* xhi  = (ushort*)ws; ws += NF * 2;
  ushort* xlo  = (ushort*)ws; ws += NF * 2;
  float*  sqn  = (float*)ws;  ws += NP_ * 4;
  int*    nbr  = (int*)ws;    ws += NP_ * K_ * 4;
  float*  gsum = (float*)ws;  ws += (size_t)B_ * H_ * 4;
  float*  pd   = (float*)ws;  ws += NP_ * 64 * 4;
  float*  tau  = (float*)ws;  ws += NP_ * 4;
  int*    cnt  = (int*)ws;    ws += NP_ * 4 * 4;
  float4* pt4  = (float4*)ws; ws += NP_ * 16;
  float2* cand = (float2*)ws; ws += NP_ * (size_t)(4 * CAPQ) * 8;

  const int NP = B_ * P_;
  dim3 blk256(256), blk128(128);

  // ---- layer 1 (D=3)
  pack4_kernel<<<NP / 256, blk256, 0, stream>>>(x, pt4);
  feat_kernel<3><<<NP / 8, blk256, 0, stream>>>(x, W1, b1, bufA, bufU);
  knn3_part_kernel<<<B_ * 64, blk256, 0, stream>>>(pt4, pd);
  tau_kernel<<<NP / 256, blk256, 0, stream>>>(pd, tau);
  knn3_compact_kernel<<<B_ * 64 * 4, blk256, 0, stream>>>(pt4, tau, cand, cnt);
  knn_select_kernel<<<NP / 4, blk256, 0, stream>>>(cand, cnt, nbr);
  aggr_kernel<<<(NP * H_) / 256, blk256, 0, stream>>>(bufA, bufU, nbr, bufA);

  // ---- layer 2 (D=128), X = bufA
  split_kernel<<<(int)(NF / 4 / 256), blk256, 0, stream>>>(bufA, xhi, xlo);
  sq_kernel<128><<<NP / 256, blk256, 0, stream>>>(bufA, sqn);
  feat_kernel<128><<<NP / 8, blk256, 0, stream>>>(bufA, W2, b2, bufB, bufU);
  knn_part_kernel<<<B_ * 64, blk256, 0, stream>>>(xhi, xlo, sqn, pd);
  tau_kernel<<<NP / 256, blk256, 0, stream>>>(pd, tau);
  knn_compact_kernel<<<B_ * 64 * 2, blk256, 0, stream>>>(xhi, xlo, sqn, tau, cand, cnt);
  knn_select_kernel<<<NP / 4, blk256, 0, stream>>>(cand, cnt, nbr);
  aggr_kernel<<<(NP * H_) / 256, blk256, 0, stream>>>(bufB, bufU, nbr, bufB);

  // ---- layer 3 (D=128), X = bufB
  split_kernel<<<(int)(NF / 4 / 256), blk256, 0, stream>>>(bufB, xhi, xlo);
  sq_kernel<128><<<NP / 256, blk256, 0, stream>>>(bufB, sqn);
  feat_kernel<128><<<NP / 8, blk256, 0, stream>>>(bufB, W3, b3, bufA, bufU);
  knn_part_kernel<<<B_ * 64, blk256, 0, stream>>>(xhi, xlo, sqn, pd);
  tau_kernel<<<NP / 256, blk256, 0, stream>>>(pd, tau);
  knn_compact_kernel<<<B_ * 64 * 2, blk256, 0, stream>>>(xhi, xlo, sqn, tau, cand, cnt);
  knn_select_kernel<<<NP / 4, blk256, 0, stream>>>(cand, cnt, nbr);
  aggr_kernel<<<(NP * H_) / 256, blk256, 0, stream>>>(bufA, bufU, nbr, bufA);

  // ---- head
  zero_kernel<<<(B_ * H_) / 256, blk256, 0, stream>>>(gsum);
  pool_kernel<<<B_ * (P_ / 64), blk128, 0, stream>>>(bufA, gsum);
  head_kernel<<<B_, blk128, 0, stream>>>(gsum, W4, b4, W5, b5, out);
}